// Round 5
// baseline (829.413 us; speedup 1.0000x reference)
//
#include <hip/hip_runtime.h>

#define NN 50000
#define NE 400000

typedef unsigned int u32;
typedef unsigned short u16;
typedef __attribute__((ext_vector_type(8))) short short8; // 8 bf16 = 4 VGPR
typedef __attribute__((ext_vector_type(4))) float f32x4;

union FragU { uint4 u; short8 s; };
union Chunk { uint4 v[4]; u32 d[16]; };

__device__ __forceinline__ float bflo(u32 w){ union{u32 i; float f;} v; v.i = w<<16; return v.f; }
__device__ __forceinline__ float bfhi(u32 w){ union{u32 i; float f;} v; v.i = w & 0xffff0000u; return v.f; }
__device__ __forceinline__ u32 packbf(float a, float b){
  union{float f;u32 i;} x, y; x.f=a; y.f=b;
  u32 xi = x.i + (((x.i>>16)&1u) + 0x7fffu);
  u32 yi = y.i + (((y.i>>16)&1u) + 0x7fffu);
  return (xi>>16) | (yi & 0xffff0000u);
}

// swizzled dword index in a [rows][128]-bf16 tile (64 u32/row)
__device__ __forceinline__ int swz64(int row, int cp){ return row*64 + (cp ^ ((row&7)<<2)); }
// same for [rows][256]-bf16 tile (128 u32/row)
__device__ __forceinline__ int swz128(int row, int cp){ return row*128 + (cp ^ ((row&7)<<2)); }

// Stage 64 rows (f32, stride 128) with LayerNorm -> bf16 swizzled tile. 4 threads/row.
// Optionally save raw rows into einT (LDS, float4-chunk XOR-swizzled) for the residual.
template<bool RAW>
__device__ __forceinline__ void stage_ln(const float* __restrict__ src, long base, long nrows,
                                         const float* __restrict__ gam, const float* __restrict__ bet,
                                         u32* __restrict__ tile, float4* __restrict__ einT, int t)
{
  int row = t>>2, sub = t&3;
  bool valid = (base + row) < nrows;
  const float* p = src + (base+row)*128 + sub*32;
  float4 x[8];
  float s=0.f, s2=0.f;
  #pragma unroll
  for(int q=0;q<8;++q){
    x[q] = valid ? *(const float4*)(p + 4*q) : make_float4(0.f,0.f,0.f,0.f);
    if (RAW) einT[row*32 + ((sub*8+q) ^ (row&7))] = x[q];
    s  += x[q].x + x[q].y + x[q].z + x[q].w;
    s2 += x[q].x*x[q].x + x[q].y*x[q].y + x[q].z*x[q].z + x[q].w*x[q].w;
  }
  s  += __shfl_xor(s,1);  s  += __shfl_xor(s,2);
  s2 += __shfl_xor(s2,1); s2 += __shfl_xor(s2,2);
  float mu  = s*(1.f/128.f);
  float var = fmaxf(s2*(1.f/128.f) - mu*mu, 0.f);
  float rs  = rsqrtf(var + 1e-5f);
  const float* gp = gam + sub*32; const float* bp = bet + sub*32;
  #pragma unroll
  for(int m4=0;m4<4;++m4){
    float4 g0 = *(const float4*)(gp + 8*m4);
    float4 g1 = *(const float4*)(gp + 8*m4 + 4);
    float4 b0 = *(const float4*)(bp + 8*m4);
    float4 b1 = *(const float4*)(bp + 8*m4 + 4);
    float4 xa = x[2*m4], xb = x[2*m4+1];
    uint4 wv;
    wv.x = packbf((xa.x-mu)*rs*g0.x+b0.x, (xa.y-mu)*rs*g0.y+b0.y);
    wv.y = packbf((xa.z-mu)*rs*g0.z+b0.z, (xa.w-mu)*rs*g0.w+b0.w);
    wv.z = packbf((xb.x-mu)*rs*g1.x+b1.x, (xb.y-mu)*rs*g1.y+b1.y);
    wv.w = packbf((xb.z-mu)*rs*g1.z+b1.z, (xb.w-mu)*rs*g1.w+b1.w);
    *(uint4*)&tile[swz64(row, sub*16 + m4*4)] = wv;
  }
}

// D^T = W^T (A-op, packed PW) x data (B-op from swizzled tile). 8 mt tiles, K=128.
__device__ __forceinline__ void gemmT8(const u16* __restrict__ PW, int NT, int mtoff,
                                       const u32* __restrict__ tile, int row, int l,
                                       f32x4 acc[8])
{
  int g = l>>4;
  #pragma unroll
  for(int kc=0;kc<4;++kc){
    FragU bf; bf.u = *(const uint4*)&tile[swz64(row, kc*16 + g*4)];
    #pragma unroll
    for(int mt=0;mt<8;++mt){
      FragU af; af.u = ((const uint4*)PW)[(size_t)(kc*NT + mtoff + mt)*64 + l];
      acc[mt] = __builtin_amdgcn_mfma_f32_16x16x32_bf16(af.s, bf.s, acc[mt], 0,0,0);
    }
  }
}

// K=256 variant (8 kc) reading from [64][256] tile
__device__ __forceinline__ void gemmT8_k256(const u16* __restrict__ PW,
                                            const u32* __restrict__ tile, int row, int l,
                                            f32x4 acc[8])
{
  int g = l>>4;
  #pragma unroll
  for(int kc=0;kc<8;++kc){
    FragU bf; bf.u = *(const uint4*)&tile[swz128(row, kc*16 + g*4)];
    #pragma unroll
    for(int mt=0;mt<8;++mt){
      FragU af; af.u = ((const uint4*)PW)[(size_t)(kc*8 + mt)*64 + l];
      acc[mt] = __builtin_amdgcn_mfma_f32_16x16x32_bf16(af.s, bf.s, acc[mt], 0,0,0);
    }
  }
}

// Pack f32 weight [K][N] into MFMA A-fragment order (bf16)
__global__ __launch_bounds__(256)
void k_pack(const float* __restrict__ src, u16* __restrict__ dst, int K, int N){
  int i = blockIdx.x*256 + threadIdx.x;
  if (i >= K*N) return;
  int j = i & 7, l = (i>>3) & 63;
  int rest = i >> 9;
  int NT = N >> 4;
  int nt = rest % NT, kc = rest / NT;
  int k = kc*32 + (l>>4)*8 + j;
  int n = nt*16 + (l&15);
  union{float f;u32 u;} x; x.f = src[(size_t)k*N + n];
  u32 r = (x.u + (((x.u>>16)&1u) + 0x7fffu)) >> 16;
  dst[i] = (u16)r;
}

// ---------------- CSR build ----------------
__global__ __launch_bounds__(256)
void k_deg(const int* __restrict__ eidx, int* __restrict__ deg){
  int e = blockIdx.x*256 + threadIdx.x;
  if (e < NE) atomicAdd(&deg[eidx[NE+e]], 1);
}

__global__ __launch_bounds__(1024)
void k_scan(const int* __restrict__ deg, int* __restrict__ starts, int* __restrict__ cursor){
  __shared__ int part[1024];
  int t = threadIdx.x;
  const int CH = (NN + 1023)/1024;
  int base = t*CH;
  int s = 0;
  for (int i=0;i<CH;++i){ int idx = base+i; if (idx < NN) s += deg[idx]; }
  part[t] = s; __syncthreads();
  for (int off=1; off<1024; off<<=1){
    int v = (t>=off) ? part[t-off] : 0;
    __syncthreads();
    part[t] += v;
    __syncthreads();
  }
  int pre = (t==0) ? 0 : part[t-1];
  for (int i=0;i<CH;++i){
    int idx = base+i;
    if (idx < NN){ starts[idx]=pre; cursor[idx]=pre; pre += deg[idx]; }
  }
}

__global__ __launch_bounds__(256)
void k_scatter(const int* __restrict__ eidx, int* __restrict__ cursor, int* __restrict__ perm){
  int e = blockIdx.x*256 + threadIdx.x;
  if (e < NE){
    int d = eidx[NE+e];
    perm[e] = atomicAdd(&cursor[d], 1);
  }
}

// ---------------- K1: node LN + q,k,v projections ----------------
// q/k/v rows stored PERMUTED: dword (g*16 + mt*2 + j2) holds feats mt*16+g*4+2*j2 {lo,hi}.
// => one lane's 8 uint2 fragments are 16 contiguous dwords (64B).
__global__ __launch_bounds__(256)
void k_qkv(const float* __restrict__ xin,
           const float* __restrict__ l1g, const float* __restrict__ l1b,
           const u16* __restrict__ pWq, const float* __restrict__ bq,
           const u16* __restrict__ pWk, const float* __restrict__ bk,
           const u16* __restrict__ pWv, const float* __restrict__ bv,
           u32* __restrict__ qv, u32* __restrict__ kv, u32* __restrict__ vv)
{
  __shared__ u32 tile[64*64];
  int t = threadIdx.x;
  long base = (long)blockIdx.x * 64;
  stage_ln<false>(xin, base, NN, l1g, l1b, tile, nullptr, t);
  __syncthreads();
  int w = t>>6, l = t&63, g = l>>4;
  int row = w*16 + (l&15);
  long node = base + row;
  bool valid = node < NN;

  f32x4 acc[8];
  const u16* pws[3] = {pWq, pWk, pWv};
  const float* bbs[3] = {bq, bk, bv};
  u32* outs[3] = {qv, kv, vv};
  #pragma unroll
  for(int s3=0;s3<3;++s3){
    #pragma unroll
    for(int mt=0;mt<8;++mt) acc[mt] = (f32x4){0.f,0.f,0.f,0.f};
    gemmT8(pws[s3], 8, 0, tile, row, l, acc);
    if (valid){
      Chunk c;
      #pragma unroll
      for(int mt=0;mt<8;++mt){
        float4 bb = *(const float4*)(bbs[s3] + mt*16 + g*4);
        c.d[mt*2]   = packbf(acc[mt][0]+bb.x, acc[mt][1]+bb.y);
        c.d[mt*2+1] = packbf(acc[mt][2]+bb.z, acc[mt][3]+bb.w);
      }
      uint4* op = (uint4*)(outs[s3] + node*64 + g*16);
      #pragma unroll
      for(int i=0;i<4;++i) op[i] = c.v[i];
    }
  }
}

// ---------------- K2: fused edge pass (atomic-free, CSR-ordered side outputs) -------
__global__ __launch_bounds__(256)
void k_edge(const float* __restrict__ ein,
            const float* __restrict__ l1eg, const float* __restrict__ l1eb,
            const u16* __restrict__ pWg, const float* __restrict__ bg,
            const u16* __restrict__ pWe, const float* __restrict__ be,
            const u16* __restrict__ pWoe, const float* __restrict__ boe,
            const int* __restrict__ eidx, const int* __restrict__ perm,
            const u32* __restrict__ qv, const u32* __restrict__ kv, const u32* __restrict__ vv,
            u32* __restrict__ gvp, float* __restrict__ escp,
            float* __restrict__ eout)
{
  __shared__ u32 tile[64*64];
  __shared__ float4 einT[64*32];
  int t = threadIdx.x;
  long base = (long)blockIdx.x * 64;
  stage_ln<true>(ein, base, NE, l1eg, l1eb, tile, einT, t);

  int w = t>>6, l = t&63, g = l>>4;
  int row = w*16 + (l&15);
  long edge = base + row;
  int s_ = eidx[edge], d_ = eidx[NE + edge];
  int pos = perm[edge];
  __syncthreads();

  // issue q/k gathers (contiguous 64B per lane) -- they fly under the Wg GEMM
  const uint4* qp = (const uint4*)(qv + (size_t)d_*64 + g*16);
  const uint4* kp = (const uint4*)(kv + (size_t)s_*64 + g*16);
  Chunk qc, kc;
  #pragma unroll
  for(int i=0;i<4;++i){ qc.v[i] = qp[i]; kc.v[i] = kp[i]; }

  f32x4 acc[8], gate[8];
  // gate = sigmoid(LN(e)@Wg + bg)
  #pragma unroll
  for(int mt=0;mt<8;++mt) acc[mt] = (f32x4){0.f,0.f,0.f,0.f};
  gemmT8(pWg, 8, 0, tile, row, l, acc);
  #pragma unroll
  for(int mt=0;mt<8;++mt){
    float4 bb = *(const float4*)(bg + mt*16 + g*4);
    gate[mt][0] = 1.f/(1.f+__expf(-(acc[mt][0]+bb.x)));
    gate[mt][1] = 1.f/(1.f+__expf(-(acc[mt][1]+bb.y)));
    gate[mt][2] = 1.f/(1.f+__expf(-(acc[mt][2]+bb.z)));
    gate[mt][3] = 1.f/(1.f+__expf(-(acc[mt][3]+bb.w)));
  }
  // issue v gather; flies under the We GEMM
  const uint4* vp = (const uint4*)(vv + (size_t)s_*64 + g*16);
  Chunk vc;
  #pragma unroll
  for(int i=0;i<4;++i) vc.v[i] = vp[i];

  // s_elt = LN(e)@We + be + q[dst]*k[src]
  #pragma unroll
  for(int mt=0;mt<8;++mt) acc[mt] = (f32x4){0.f,0.f,0.f,0.f};
  gemmT8(pWe, 8, 0, tile, row, l, acc);
  float esc[8];
  #pragma unroll
  for(int mt=0;mt<8;++mt){
    float4 bb = *(const float4*)(be + mt*16 + g*4);
    u32 q0 = qc.d[mt*2], q1 = qc.d[mt*2+1];
    u32 k0 = kc.d[mt*2], k1 = kc.d[mt*2+1];
    acc[mt][0] += bb.x + bflo(q0)*bflo(k0);
    acc[mt][1] += bb.y + bfhi(q0)*bfhi(k0);
    acc[mt][2] += bb.z + bflo(q1)*bflo(k1);
    acc[mt][3] += bb.w + bfhi(q1)*bfhi(k1);
    float ps = acc[mt][0]+acc[mt][1]+acc[mt][2]+acc[mt][3];
    ps += __shfl_xor(ps, 16);
    ps += __shfl_xor(ps, 32);                  // sum over all 16 feats of head mt
    float sc = fminf(fmaxf(ps*0.25f, -5.f), 5.f);
    esc[mt] = __expf(sc);                      // clipped => no max-subtract needed
  }
  // store esc [pos][8] f32 (one lane per edge)
  if (g==0){
    float4 e0 = {esc[0],esc[1],esc[2],esc[3]};
    float4 e1 = {esc[4],esc[5],esc[6],esc[7]};
    *(float4*)(escp + (size_t)pos*8)     = e0;
    *(float4*)(escp + (size_t)pos*8 + 4) = e1;
  }
  // store gv = gate (x) v[src]  (bf16, CSR position, permuted row layout, 64B/lane)
  {
    Chunk gc;
    #pragma unroll
    for(int mt=0;mt<8;++mt){
      u32 v0 = vc.d[mt*2], v1 = vc.d[mt*2+1];
      gc.d[mt*2]   = packbf(gate[mt][0]*bflo(v0), gate[mt][1]*bfhi(v0));
      gc.d[mt*2+1] = packbf(gate[mt][2]*bflo(v1), gate[mt][3]*bfhi(v1));
    }
    uint4* gp = (uint4*)(gvp + (size_t)pos*64 + g*16);
    #pragma unroll
    for(int i=0;i<4;++i) gp[i] = gc.v[i];
  }
  __syncthreads();                 // all waves done reading LN tile
  // write s_elt (bf16) into tile (B-layout for Woe GEMM)
  #pragma unroll
  for(int mt=0;mt<8;++mt){
    uint2 o;
    o.x = packbf(acc[mt][0], acc[mt][1]);
    o.y = packbf(acc[mt][2], acc[mt][3]);
    *(uint2*)&tile[swz64(row, mt*8 + g*2)] = o;
  }
  __syncthreads();
  // e_out = e_in + s_elt@Woe + boe   (e_in residual from LDS)
  f32x4 oacc[8];
  #pragma unroll
  for(int mt=0;mt<8;++mt) oacc[mt] = (f32x4){0.f,0.f,0.f,0.f};
  gemmT8(pWoe, 8, 0, tile, row, l, oacc);
  #pragma unroll
  for(int mt=0;mt<8;++mt){
    float4 bb = *(const float4*)(boe + mt*16 + g*4);
    float4 er = einT[row*32 + ((mt*4+g) ^ (row&7))];
    float4 o;
    o.x = er.x + oacc[mt][0] + bb.x;
    o.y = er.y + oacc[mt][1] + bb.y;
    o.z = er.z + oacc[mt][2] + bb.z;
    o.w = er.w + oacc[mt][3] + bb.w;
    *(float4*)(eout + edge*128 + mt*16 + g*4) = o;
  }
}

// ---------------- K2b: per-node aggregation, fully sequential reads ----------------
__global__ __launch_bounds__(256)
void k_agg(const u32* __restrict__ gvp, const float* __restrict__ escp,
           const int* __restrict__ starts, const int* __restrict__ ends,
           float* __restrict__ xattn)
{
  int w = threadIdx.x>>6, l = threadIdx.x&63;
  long n = (long)blockIdx.x*4 + w;
  if (n >= NN) return;
  int g = l>>4, mt = (l&15)>>1, j2 = l&1;   // permuted-row dword l -> feats mt*16+g*4+2*j2
  int s = starts[n], e = ends[n];
  float s0=0.f, s1=0.f, den=0.f;
  for (int i=s;i<e;++i){
    u32 gvw = gvp[(size_t)i*64 + l];
    float a = escp[(size_t)i*8 + mt];
    s0 += a*bflo(gvw);
    s1 += a*bfhi(gvw);
    den += a;
  }
  float inv = den>0.f ? 1.f/den : 0.f;  // zero in-degree -> 0 (segment_sum semantics)
  float2 o; o.x = s0*inv; o.y = s1*inv;
  *(float2*)(xattn + n*128 + mt*16 + g*4 + 2*j2) = o;
}

// ---------------- K3: node epilogue: Wo, LN2, FFN ----------------
__global__ __launch_bounds__(256)
void k_out(const float* __restrict__ xin,
           const float* __restrict__ accN,
           const u16* __restrict__ pWo, const float* __restrict__ bo,
           const float* __restrict__ l2g, const float* __restrict__ l2b,
           const u16* __restrict__ pW1, const float* __restrict__ b1p,
           const u16* __restrict__ pW2, const float* __restrict__ b2p,
           float* __restrict__ xout)
{
  __shared__ u32 tile[64*64];
  __shared__ u32 htile[64*128];
  int t = threadIdx.x;
  long base = (long)blockIdx.x * 64;
  // stage normalized attention output -> bf16 tile
  {
    int row = t>>2, sub = t&3;
    long node = base + row;
    bool valid = node < NN;
    const float* p = accN + node*128 + sub*32;
    #pragma unroll
    for(int m4=0;m4<4;++m4){
      float4 xa = valid ? *(const float4*)(p + 8*m4)     : make_float4(0.f,0.f,0.f,0.f);
      float4 xb = valid ? *(const float4*)(p + 8*m4 + 4) : make_float4(0.f,0.f,0.f,0.f);
      uint4 wv;
      wv.x = packbf(xa.x, xa.y);
      wv.y = packbf(xa.z, xa.w);
      wv.z = packbf(xb.x, xb.y);
      wv.w = packbf(xb.z, xb.w);
      *(uint4*)&tile[swz64(row, sub*16 + m4*4)] = wv;
    }
  }
  __syncthreads();
  int w = t>>6, l = t&63, g = l>>4;
  int row = w*16 + (l&15);
  long node = base + row;
  bool valid = node < NN;

  // Wo GEMM; xmid = x_in + out@Wo + bo
  f32x4 acc[8], xm[8];
  #pragma unroll
  for(int mt=0;mt<8;++mt) acc[mt] = (f32x4){0.f,0.f,0.f,0.f};
  gemmT8(pWo, 8, 0, tile, row, l, acc);
  #pragma unroll
  for(int mt=0;mt<8;++mt){
    float4 bb = *(const float4*)(bo + mt*16 + g*4);
    float4 xr = valid ? *(const float4*)(xin + node*128 + mt*16 + g*4) : make_float4(0.f,0.f,0.f,0.f);
    xm[mt][0] = xr.x + acc[mt][0] + bb.x;
    xm[mt][1] = xr.y + acc[mt][1] + bb.y;
    xm[mt][2] = xr.z + acc[mt][2] + bb.z;
    xm[mt][3] = xr.w + acc[mt][3] + bb.w;
  }
  // LN2 in-register
  float s=0.f, s2=0.f;
  #pragma unroll
  for(int mt=0;mt<8;++mt){
    s  += xm[mt][0]+xm[mt][1]+xm[mt][2]+xm[mt][3];
    s2 += xm[mt][0]*xm[mt][0]+xm[mt][1]*xm[mt][1]+xm[mt][2]*xm[mt][2]+xm[mt][3]*xm[mt][3];
  }
  s  += __shfl_xor(s,16);  s  += __shfl_xor(s,32);
  s2 += __shfl_xor(s2,16); s2 += __shfl_xor(s2,32);
  float mu  = s*(1.f/128.f);
  float var = fmaxf(s2*(1.f/128.f) - mu*mu, 0.f);
  float rs  = rsqrtf(var + 1e-5f);
  __syncthreads();              // done reading tile (Wo B-frags)
  #pragma unroll
  for(int mt=0;mt<8;++mt){
    float4 gg = *(const float4*)(l2g + mt*16 + g*4);
    float4 bb = *(const float4*)(l2b + mt*16 + g*4);
    float h0 = (xm[mt][0]-mu)*rs*gg.x + bb.x;
    float h1 = (xm[mt][1]-mu)*rs*gg.y + bb.y;
    float h2 = (xm[mt][2]-mu)*rs*gg.z + bb.z;
    float h3 = (xm[mt][3]-mu)*rs*gg.w + bb.w;
    uint2 o; o.x = packbf(h0,h1); o.y = packbf(h2,h3);
    *(uint2*)&tile[swz64(row, mt*8 + g*2)] = o;
  }
  __syncthreads();
  // FFN layer 1 (256 outs in two halves), relu -> htile
  #pragma unroll
  for(int half=0; half<2; ++half){
    f32x4 dh[8];
    #pragma unroll
    for(int mt=0;mt<8;++mt) dh[mt] = (f32x4){0.f,0.f,0.f,0.f};
    gemmT8(pW1, 16, half*8, tile, row, l, dh);
    #pragma unroll
    for(int mt=0;mt<8;++mt){
      int feat = half*128 + mt*16 + g*4;
      float4 bb = *(const float4*)(b1p + feat);
      float h0 = fmaxf(dh[mt][0]+bb.x, 0.f);
      float h1 = fmaxf(dh[mt][1]+bb.y, 0.f);
      float h2 = fmaxf(dh[mt][2]+bb.z, 0.f);
      float h3 = fmaxf(dh[mt][3]+bb.w, 0.f);
      uint2 o; o.x = packbf(h0,h1); o.y = packbf(h2,h3);
      *(uint2*)&htile[swz128(row, feat>>1)] = o;
    }
  }
  __syncthreads();
  // FFN layer 2 (K=256) + residual
  f32x4 oacc[8];
  #pragma unroll
  for(int mt=0;mt<8;++mt) oacc[mt] = (f32x4){0.f,0.f,0.f,0.f};
  gemmT8_k256(pW2, htile, row, l, oacc);
  if (valid){
    #pragma unroll
    for(int mt=0;mt<8;++mt){
      float4 bb = *(const float4*)(b2p + mt*16 + g*4);
      float4 o;
      o.x = xm[mt][0] + oacc[mt][0] + bb.x;
      o.y = xm[mt][1] + oacc[mt][1] + bb.y;
      o.z = xm[mt][2] + oacc[mt][2] + bb.z;
      o.w = xm[mt][3] + oacc[mt][3] + bb.w;
      *(float4*)(xout + node*128 + mt*16 + g*4) = o;
    }
  }
}

extern "C" void kernel_launch(void* const* d_in, const int* in_sizes, int n_in,
                              void* d_out, int out_size, void* d_ws, size_t ws_size,
                              hipStream_t stream) {
  (void)in_sizes; (void)n_in; (void)out_size; (void)ws_size;
  const float* xin = (const float*)d_in[0];
  const float* ein = (const float*)d_in[1];
  const float* Wq = (const float*)d_in[2];  const float* bq = (const float*)d_in[3];
  const float* Wk = (const float*)d_in[4];  const float* bk = (const float*)d_in[5];
  const float* Wv = (const float*)d_in[6];  const float* bv = (const float*)d_in[7];
  const float* We = (const float*)d_in[8];  const float* be = (const float*)d_in[9];
  const float* Wg = (const float*)d_in[10]; const float* bg = (const float*)d_in[11];
  const float* Wo = (const float*)d_in[12]; const float* bo = (const float*)d_in[13];
  const float* Woe= (const float*)d_in[14]; const float* boe= (const float*)d_in[15];
  const float* l1g= (const float*)d_in[16]; const float* l1b= (const float*)d_in[17];
  const float* l1eg=(const float*)d_in[18]; const float* l1eb=(const float*)d_in[19];
  const float* l2g= (const float*)d_in[20]; const float* l2b= (const float*)d_in[21];
  const float* W1 = (const float*)d_in[22]; const float* b1 = (const float*)d_in[23];
  const float* W2 = (const float*)d_in[24]; const float* b2 = (const float*)d_in[25];
  const int* eidx = (const int*)d_in[26];

  float* xout = (float*)d_out;
  float* eout = xout + (size_t)NN*128;
  float* xattn = xout;                       // x_out region holds normalized attn out

  // ws: esc [NE*8 f32] | gv [NE*64 u32] | qv,kv,vv [NN*64 u32] | deg,starts,cursor [NN] | perm [NE] | packed W
  float* escp = (float*)d_ws;
  u32* gvp = (u32*)(escp + (size_t)NE*8);
  u32* qv = gvp + (size_t)NE*64;
  u32* kv = qv + (size_t)NN*64;
  u32* vv = kv + (size_t)NN*64;
  int* deg = (int*)(vv + (size_t)NN*64);
  int* starts = deg + NN;
  int* cursor = starts + NN;
  int* perm = cursor + NN;
  u16* pw  = (u16*)(perm + NE);
  u16* pWq = pw;            u16* pWk = pWq + 16384;  u16* pWv = pWk + 16384;
  u16* pWe = pWv + 16384;   u16* pWg = pWe + 16384;  u16* pWoe= pWg + 16384;
  u16* pWo = pWoe + 16384;  u16* pW1 = pWo + 16384;  u16* pW2 = pW1 + 32768;

  k_pack<<<64, 256, 0, stream>>>(Wq,  pWq, 128, 128);
  k_pack<<<64, 256, 0, stream>>>(Wk,  pWk, 128, 128);
  k_pack<<<64, 256, 0, stream>>>(Wv,  pWv, 128, 128);
  k_pack<<<64, 256, 0, stream>>>(We,  pWe, 128, 128);
  k_pack<<<64, 256, 0, stream>>>(Wg,  pWg, 128, 128);
  k_pack<<<64, 256, 0, stream>>>(Woe, pWoe,128, 128);
  k_pack<<<64, 256, 0, stream>>>(Wo,  pWo, 128, 128);
  k_pack<<<128,256, 0, stream>>>(W1,  pW1, 128, 256);
  k_pack<<<128,256, 0, stream>>>(W2,  pW2, 256, 128);

  // CSR build
  hipMemsetAsync(deg, 0, NN*sizeof(int), stream);
  k_deg<<<(NE+255)/256, 256, 0, stream>>>(eidx, deg);
  k_scan<<<1, 1024, 0, stream>>>(deg, starts, cursor);
  k_scatter<<<(NE+255)/256, 256, 0, stream>>>(eidx, cursor, perm);

  k_qkv<<<(NN+63)/64, 256, 0, stream>>>(xin, l1g, l1b, pWq, bq, pWk, bk, pWv, bv, qv, kv, vv);
  k_edge<<<NE/64, 256, 0, stream>>>(ein, l1eg, l1eb, pWg, bg, pWe, be, pWoe, boe,
                                    eidx, perm, qv, kv, vv, gvp, escp, eout);
  k_agg<<<(NN+3)/4, 256, 0, stream>>>(gvp, escp, starts, cursor, xattn);
  k_out<<<(NN+63)/64, 256, 0, stream>>>(xin, xattn, pWo, bo, l2g, l2b,
                                        pW1, b1, pW2, b2, xout);
}

// Round 6
// 810.752 us; speedup vs baseline: 1.0230x; 1.0230x over previous
//
#include <hip/hip_runtime.h>

#define NN 50000
#define NE 400000

typedef unsigned int u32;
typedef unsigned short u16;
typedef __attribute__((ext_vector_type(8))) short short8; // 8 bf16 = 4 VGPR
typedef __attribute__((ext_vector_type(4))) float f32x4;

union FragU { uint4 u; short8 s; };
union Chunk { uint4 v[4]; u32 d[16]; };

__device__ __forceinline__ float bflo(u32 w){ union{u32 i; float f;} v; v.i = w<<16; return v.f; }
__device__ __forceinline__ float bfhi(u32 w){ union{u32 i; float f;} v; v.i = w & 0xffff0000u; return v.f; }
__device__ __forceinline__ u32 packbf(float a, float b){
  union{float f;u32 i;} x, y; x.f=a; y.f=b;
  u32 xi = x.i + (((x.i>>16)&1u) + 0x7fffu);
  u32 yi = y.i + (((y.i>>16)&1u) + 0x7fffu);
  return (xi>>16) | (yi & 0xffff0000u);
}

// swizzled dword index in a [rows][128]-bf16 tile (64 u32/row)
__device__ __forceinline__ int swz64(int row, int cp){ return row*64 + (cp ^ ((row&7)<<2)); }
// same for [rows][256]-bf16 tile (128 u32/row)
__device__ __forceinline__ int swz128(int row, int cp){ return row*128 + (cp ^ ((row&7)<<2)); }

// Stage 64 rows (f32, stride 128) with LayerNorm -> bf16 swizzled tile. 4 threads/row.
__device__ __forceinline__ void stage_ln(const float* __restrict__ src, long base, long nrows,
                                         const float* __restrict__ gam, const float* __restrict__ bet,
                                         u32* __restrict__ tile, int t)
{
  int row = t>>2, sub = t&3;
  bool valid = (base + row) < nrows;
  const float* p = src + (base+row)*128 + sub*32;
  float4 x[8];
  float s=0.f, s2=0.f;
  #pragma unroll
  for(int q=0;q<8;++q){
    x[q] = valid ? *(const float4*)(p + 4*q) : make_float4(0.f,0.f,0.f,0.f);
    s  += x[q].x + x[q].y + x[q].z + x[q].w;
    s2 += x[q].x*x[q].x + x[q].y*x[q].y + x[q].z*x[q].z + x[q].w*x[q].w;
  }
  s  += __shfl_xor(s,1);  s  += __shfl_xor(s,2);
  s2 += __shfl_xor(s2,1); s2 += __shfl_xor(s2,2);
  float mu  = s*(1.f/128.f);
  float var = fmaxf(s2*(1.f/128.f) - mu*mu, 0.f);
  float rs  = rsqrtf(var + 1e-5f);
  const float* gp = gam + sub*32; const float* bp = bet + sub*32;
  #pragma unroll
  for(int m4=0;m4<4;++m4){
    float4 g0 = *(const float4*)(gp + 8*m4);
    float4 g1 = *(const float4*)(gp + 8*m4 + 4);
    float4 b0 = *(const float4*)(bp + 8*m4);
    float4 b1 = *(const float4*)(bp + 8*m4 + 4);
    float4 xa = x[2*m4], xb = x[2*m4+1];
    uint4 wv;
    wv.x = packbf((xa.x-mu)*rs*g0.x+b0.x, (xa.y-mu)*rs*g0.y+b0.y);
    wv.y = packbf((xa.z-mu)*rs*g0.z+b0.z, (xa.w-mu)*rs*g0.w+b0.w);
    wv.z = packbf((xb.x-mu)*rs*g1.x+b1.x, (xb.y-mu)*rs*g1.y+b1.y);
    wv.w = packbf((xb.z-mu)*rs*g1.z+b1.z, (xb.w-mu)*rs*g1.w+b1.w);
    *(uint4*)&tile[swz64(row, sub*16 + m4*4)] = wv;
  }
}

// D^T = W^T (A-op, packed PW) x data (B-op from swizzled tile). 8 mt tiles, K=128.
__device__ __forceinline__ void gemmT8(const u16* __restrict__ PW, int NT, int mtoff,
                                       const u32* __restrict__ tile, int row, int l,
                                       f32x4 acc[8])
{
  int g = l>>4;
  #pragma unroll
  for(int kc=0;kc<4;++kc){
    FragU bf; bf.u = *(const uint4*)&tile[swz64(row, kc*16 + g*4)];
    #pragma unroll
    for(int mt=0;mt<8;++mt){
      FragU af; af.u = ((const uint4*)PW)[(size_t)(kc*NT + mtoff + mt)*64 + l];
      acc[mt] = __builtin_amdgcn_mfma_f32_16x16x32_bf16(af.s, bf.s, acc[mt], 0,0,0);
    }
  }
}

// K=256 variant (8 kc) reading from [64][256] tile
__device__ __forceinline__ void gemmT8_k256(const u16* __restrict__ PW,
                                            const u32* __restrict__ tile, int row, int l,
                                            f32x4 acc[8])
{
  int g = l>>4;
  #pragma unroll
  for(int kc=0;kc<8;++kc){
    FragU bf; bf.u = *(const uint4*)&tile[swz128(row, kc*16 + g*4)];
    #pragma unroll
    for(int mt=0;mt<8;++mt){
      FragU af; af.u = ((const uint4*)PW)[(size_t)(kc*8 + mt)*64 + l];
      acc[mt] = __builtin_amdgcn_mfma_f32_16x16x32_bf16(af.s, bf.s, acc[mt], 0,0,0);
    }
  }
}

// Pack all 9 f32 weights into MFMA A-fragment order (bf16), one launch.
__global__ __launch_bounds__(256)
void k_packall(const float* __restrict__ Wq, const float* __restrict__ Wk,
               const float* __restrict__ Wv, const float* __restrict__ We,
               const float* __restrict__ Wg, const float* __restrict__ Woe,
               const float* __restrict__ Wo, const float* __restrict__ W1,
               const float* __restrict__ W2, u16* __restrict__ dst)
{
  int i = blockIdx.x*256 + threadIdx.x;
  const float* src; int K, N, idx;
  if (i < 7*16384){
    int m = i >> 14; idx = i & 16383; K=128; N=128;
    src = (m==0)?Wq:(m==1)?Wk:(m==2)?Wv:(m==3)?We:(m==4)?Wg:(m==5)?Woe:Wo;
  } else if (i < 7*16384 + 32768){ idx = i - 7*16384; K=128; N=256; src = W1; }
  else if (i < 7*16384 + 65536){ idx = i - 7*16384 - 32768; K=256; N=128; src = W2; }
  else return;
  int j = idx & 7, l = (idx>>3) & 63;
  int rest = idx >> 9;
  int NT = N >> 4;
  int nt = rest % NT, kc = rest / NT;
  int k = kc*32 + (l>>4)*8 + j;
  int n = nt*16 + (l&15);
  union{float f;u32 u;} x; x.f = src[(size_t)k*N + n];
  dst[i] = (u16)((x.u + (((x.u>>16)&1u) + 0x7fffu)) >> 16);
}

// ---------------- CSR build ----------------
__global__ __launch_bounds__(256)
void k_deg(const int* __restrict__ eidx, int* __restrict__ deg){
  int e = blockIdx.x*256 + threadIdx.x;
  if (e < NE) atomicAdd(&deg[eidx[NE+e]], 1);
}

__global__ __launch_bounds__(1024)
void k_scan(const int* __restrict__ deg, int* __restrict__ starts, int* __restrict__ cursor){
  __shared__ int part[1024];
  int t = threadIdx.x;
  const int CH = (NN + 1023)/1024;
  int base = t*CH;
  int s = 0;
  for (int i=0;i<CH;++i){ int idx = base+i; if (idx < NN) s += deg[idx]; }
  part[t] = s; __syncthreads();
  for (int off=1; off<1024; off<<=1){
    int v = (t>=off) ? part[t-off] : 0;
    __syncthreads();
    part[t] += v;
    __syncthreads();
  }
  int pre = (t==0) ? 0 : part[t-1];
  for (int i=0;i<CH;++i){
    int idx = base+i;
    if (idx < NN){ starts[idx]=pre; cursor[idx]=pre; pre += deg[idx]; }
  }
}

__global__ __launch_bounds__(256)
void k_scatter(const int* __restrict__ eidx, int* __restrict__ cursor, int* __restrict__ perm){
  int e = blockIdx.x*256 + threadIdx.x;
  if (e < NE){
    int d = eidx[NE+e];
    perm[e] = atomicAdd(&cursor[d], 1);
  }
}

// ---------------- K1: node LN + q,k,v projections ----------------
// q/k/v rows stored PERMUTED: dword (g*16 + mt*2 + j2) holds feats mt*16+g*4+2*j2 {lo,hi}.
__global__ __launch_bounds__(256)
void k_qkv(const float* __restrict__ xin,
           const float* __restrict__ l1g, const float* __restrict__ l1b,
           const u16* __restrict__ pWq, const float* __restrict__ bq,
           const u16* __restrict__ pWk, const float* __restrict__ bk,
           const u16* __restrict__ pWv, const float* __restrict__ bv,
           u32* __restrict__ qv, u32* __restrict__ kv, u32* __restrict__ vv)
{
  __shared__ u32 tile[64*64];
  int t = threadIdx.x;
  long base = (long)blockIdx.x * 64;
  stage_ln(xin, base, NN, l1g, l1b, tile, t);
  __syncthreads();
  int w = t>>6, l = t&63, g = l>>4;
  int row = w*16 + (l&15);
  long node = base + row;
  bool valid = node < NN;

  f32x4 acc[8];
  const u16* pws[3] = {pWq, pWk, pWv};
  const float* bbs[3] = {bq, bk, bv};
  u32* outs[3] = {qv, kv, vv};
  #pragma unroll
  for(int s3=0;s3<3;++s3){
    #pragma unroll
    for(int mt=0;mt<8;++mt) acc[mt] = (f32x4){0.f,0.f,0.f,0.f};
    gemmT8(pws[s3], 8, 0, tile, row, l, acc);
    if (valid){
      Chunk c;
      #pragma unroll
      for(int mt=0;mt<8;++mt){
        float4 bb = *(const float4*)(bbs[s3] + mt*16 + g*4);
        c.d[mt*2]   = packbf(acc[mt][0]+bb.x, acc[mt][1]+bb.y);
        c.d[mt*2+1] = packbf(acc[mt][2]+bb.z, acc[mt][3]+bb.w);
      }
      uint4* op = (uint4*)(outs[s3] + node*64 + g*16);
      #pragma unroll
      for(int i=0;i<4;++i) op[i] = c.v[i];
    }
  }
}

// ---------------- K2: fused edge pass ----------------
__global__ __launch_bounds__(256)
void k_edge(const float* __restrict__ ein,
            const float* __restrict__ l1eg, const float* __restrict__ l1eb,
            const u16* __restrict__ pWg, const float* __restrict__ bg,
            const u16* __restrict__ pWe, const float* __restrict__ be,
            const u16* __restrict__ pWoe, const float* __restrict__ boe,
            const int* __restrict__ eidx, const int* __restrict__ perm,
            const u32* __restrict__ qv, const u32* __restrict__ kv, const u32* __restrict__ vv,
            u32* __restrict__ gvp, float* __restrict__ escp,
            float* __restrict__ eout)
{
  __shared__ u32 tile[64*64];
  __shared__ u32 stile[64*64];
  int t = threadIdx.x;
  long base = (long)blockIdx.x * 64;
  stage_ln(ein, base, NE, l1eg, l1eb, tile, t);

  int w = t>>6, l = t&63, g = l>>4;
  int row = w*16 + (l&15);
  long edge = base + row;
  int s_ = eidx[edge], d_ = eidx[NE + edge];
  int pos = perm[edge];
  __syncthreads();

  // issue q/k gathers (contiguous 64B per lane) -- fly under the We GEMM
  const uint4* qp = (const uint4*)(qv + (size_t)d_*64 + g*16);
  const uint4* kp = (const uint4*)(kv + (size_t)s_*64 + g*16);
  Chunk qc, kc;
  #pragma unroll
  for(int i=0;i<4;++i){ qc.v[i] = qp[i]; kc.v[i] = kp[i]; }

  // s_elt = LN(e)@We + be + q[dst]*k[src]
  f32x4 acc[8];
  #pragma unroll
  for(int mt=0;mt<8;++mt) acc[mt] = (f32x4){0.f,0.f,0.f,0.f};
  gemmT8(pWe, 8, 0, tile, row, l, acc);
  float esc[8];
  #pragma unroll
  for(int mt=0;mt<8;++mt){
    float4 bb = *(const float4*)(be + mt*16 + g*4);
    u32 q0 = qc.d[mt*2], q1 = qc.d[mt*2+1];
    u32 k0 = kc.d[mt*2], k1 = kc.d[mt*2+1];
    acc[mt][0] += bb.x + bflo(q0)*bflo(k0);
    acc[mt][1] += bb.y + bfhi(q0)*bfhi(k0);
    acc[mt][2] += bb.z + bflo(q1)*bflo(k1);
    acc[mt][3] += bb.w + bfhi(q1)*bfhi(k1);
    float ps = acc[mt][0]+acc[mt][1]+acc[mt][2]+acc[mt][3];
    ps += __shfl_xor(ps, 16);
    ps += __shfl_xor(ps, 32);                  // sum over all 16 feats of head mt
    float sc = fminf(fmaxf(ps*0.25f, -5.f), 5.f);
    esc[mt] = __expf(sc);                      // clipped => no max-subtract needed
  }
  // store esc [pos][8] f32 (one lane per edge)
  if (g==0){
    float4 e0 = {esc[0],esc[1],esc[2],esc[3]};
    float4 e1 = {esc[4],esc[5],esc[6],esc[7]};
    *(float4*)(escp + (size_t)pos*8)     = e0;
    *(float4*)(escp + (size_t)pos*8 + 4) = e1;
  }
  // write s_elt (bf16) into SEPARATE stile (B-layout for Woe GEMM)
  #pragma unroll
  for(int mt=0;mt<8;++mt){
    uint2 o;
    o.x = packbf(acc[mt][0], acc[mt][1]);
    o.y = packbf(acc[mt][2], acc[mt][3]);
    *(uint2*)&stile[swz64(row, mt*8 + g*2)] = o;
  }
  // issue v gather -- flies under the Wg GEMM
  const uint4* vp = (const uint4*)(vv + (size_t)s_*64 + g*16);
  Chunk vc;
  #pragma unroll
  for(int i=0;i<4;++i) vc.v[i] = vp[i];

  // gate = sigmoid(LN(e)@Wg + bg); gv = gate (x) v[src], stored at CSR pos
  f32x4 gacc[8];
  #pragma unroll
  for(int mt=0;mt<8;++mt) gacc[mt] = (f32x4){0.f,0.f,0.f,0.f};
  gemmT8(pWg, 8, 0, tile, row, l, gacc);
  {
    Chunk gc;
    #pragma unroll
    for(int mt=0;mt<8;++mt){
      float4 bb = *(const float4*)(bg + mt*16 + g*4);
      float g0 = 1.f/(1.f+__expf(-(gacc[mt][0]+bb.x)));
      float g1 = 1.f/(1.f+__expf(-(gacc[mt][1]+bb.y)));
      float g2 = 1.f/(1.f+__expf(-(gacc[mt][2]+bb.z)));
      float g3 = 1.f/(1.f+__expf(-(gacc[mt][3]+bb.w)));
      u32 v0 = vc.d[mt*2], v1 = vc.d[mt*2+1];
      gc.d[mt*2]   = packbf(g0*bflo(v0), g1*bfhi(v0));
      gc.d[mt*2+1] = packbf(g2*bflo(v1), g3*bfhi(v1));
    }
    uint4* gp = (uint4*)(gvp + (size_t)pos*64 + g*16);
    #pragma unroll
    for(int i=0;i<4;++i) gp[i] = gc.v[i];
  }
  __syncthreads();               // stile visible to all waves
  // e_out = e_in + s_elt@Woe + boe
  f32x4 oacc[8];
  #pragma unroll
  for(int mt=0;mt<8;++mt) oacc[mt] = (f32x4){0.f,0.f,0.f,0.f};
  gemmT8(pWoe, 8, 0, stile, row, l, oacc);
  #pragma unroll
  for(int mt=0;mt<8;++mt){
    float4 bb = *(const float4*)(boe + mt*16 + g*4);
    float4 er = *(const float4*)(ein + edge*128 + mt*16 + g*4);
    float4 o;
    o.x = er.x + oacc[mt][0] + bb.x;
    o.y = er.y + oacc[mt][1] + bb.y;
    o.z = er.z + oacc[mt][2] + bb.z;
    o.w = er.w + oacc[mt][3] + bb.w;
    *(float4*)(eout + edge*128 + mt*16 + g*4) = o;
  }
}

// ---------------- K2b: per-node aggregation, fully sequential reads ----------------
// Output: packed bf16, permuted row layout [N][64 u32]
__global__ __launch_bounds__(256)
void k_agg(const u32* __restrict__ gvp, const float* __restrict__ escp,
           const int* __restrict__ starts, const int* __restrict__ ends,
           u32* __restrict__ xattnb)
{
  int w = threadIdx.x>>6, l = threadIdx.x&63;
  long n = (long)blockIdx.x*4 + w;
  if (n >= NN) return;
  int mt = (l&15)>>1;                 // head for this permuted dword
  int s = starts[n], e = ends[n];
  float s0=0.f, s1=0.f, den=0.f;
  for (int i=s;i<e;++i){
    u32 gvw = gvp[(size_t)i*64 + l];
    float a = escp[(size_t)i*8 + mt];
    s0 += a*bflo(gvw);
    s1 += a*bfhi(gvw);
    den += a;
  }
  float inv = den>0.f ? 1.f/den : 0.f;  // zero in-degree -> 0 (segment_sum semantics)
  xattnb[n*64 + l] = packbf(s0*inv, s1*inv);
}

// ---------------- K3: node epilogue: Wo, LN2, FFN ----------------
__global__ __launch_bounds__(256)
void k_out(const float* __restrict__ xin,
           const u32* __restrict__ xattnb,
           const u16* __restrict__ pWo, const float* __restrict__ bo,
           const float* __restrict__ l2g, const float* __restrict__ l2b,
           const u16* __restrict__ pW1, const float* __restrict__ b1p,
           const u16* __restrict__ pW2, const float* __restrict__ b2p,
           float* __restrict__ xout)
{
  __shared__ u32 tile[64*64];
  __shared__ u32 htile[64*128];
  int t = threadIdx.x;
  long base = (long)blockIdx.x * 64;
  // stage attention output (packed bf16, permuted) -> swizzled tile
  {
    int row = t>>2, sub = t&3;
    long node = base + row;
    bool valid = node < NN;
    Chunk c;
    if (valid){
      const uint4* p = (const uint4*)(xattnb + node*64 + sub*16);
      #pragma unroll
      for(int i=0;i<4;++i) c.v[i] = p[i];
    } else {
      #pragma unroll
      for(int i=0;i<16;++i) c.d[i] = 0;
    }
    // permuted dword (sub*16 + mt*2 + j2) -> tile cp = mt*8 + sub*2 + j2
    #pragma unroll
    for(int mt=0;mt<8;++mt){
      uint2 o; o.x = c.d[mt*2]; o.y = c.d[mt*2+1];
      *(uint2*)&tile[swz64(row, mt*8 + sub*2)] = o;
    }
  }
  __syncthreads();
  int w = t>>6, l = t&63, g = l>>4;
  int row = w*16 + (l&15);
  long node = base + row;
  bool valid = node < NN;

  // Wo GEMM; xmid = x_in + out@Wo + bo
  f32x4 acc[8], xm[8];
  #pragma unroll
  for(int mt=0;mt<8;++mt) acc[mt] = (f32x4){0.f,0.f,0.f,0.f};
  gemmT8(pWo, 8, 0, tile, row, l, acc);
  #pragma unroll
  for(int mt=0;mt<8;++mt){
    float4 bb = *(const float4*)(bo + mt*16 + g*4);
    float4 xr = valid ? *(const float4*)(xin + node*128 + mt*16 + g*4) : make_float4(0.f,0.f,0.f,0.f);
    xm[mt][0] = xr.x + acc[mt][0] + bb.x;
    xm[mt][1] = xr.y + acc[mt][1] + bb.y;
    xm[mt][2] = xr.z + acc[mt][2] + bb.z;
    xm[mt][3] = xr.w + acc[mt][3] + bb.w;
  }
  // LN2 in-register
  float s=0.f, s2=0.f;
  #pragma unroll
  for(int mt=0;mt<8;++mt){
    s  += xm[mt][0]+xm[mt][1]+xm[mt][2]+xm[mt][3];
    s2 += xm[mt][0]*xm[mt][0]+xm[mt][1]*xm[mt][1]+xm[mt][2]*xm[mt][2]+xm[mt][3]*xm[mt][3];
  }
  s  += __shfl_xor(s,16);  s  += __shfl_xor(s,32);
  s2 += __shfl_xor(s2,16); s2 += __shfl_xor(s2,32);
  float mu  = s*(1.f/128.f);
  float var = fmaxf(s2*(1.f/128.f) - mu*mu, 0.f);
  float rs  = rsqrtf(var + 1e-5f);
  __syncthreads();              // done reading tile (Wo B-frags)
  #pragma unroll
  for(int mt=0;mt<8;++mt){
    float4 gg = *(const float4*)(l2g + mt*16 + g*4);
    float4 bb = *(const float4*)(l2b + mt*16 + g*4);
    float h0 = (xm[mt][0]-mu)*rs*gg.x + bb.x;
    float h1 = (xm[mt][1]-mu)*rs*gg.y + bb.y;
    float h2 = (xm[mt][2]-mu)*rs*gg.z + bb.z;
    float h3 = (xm[mt][3]-mu)*rs*gg.w + bb.w;
    uint2 o; o.x = packbf(h0,h1); o.y = packbf(h2,h3);
    *(uint2*)&tile[swz64(row, mt*8 + g*2)] = o;
  }
  __syncthreads();
  // FFN layer 1 (256 outs in two halves), relu -> htile
  #pragma unroll
  for(int half=0; half<2; ++half){
    f32x4 dh[8];
    #pragma unroll
    for(int mt=0;mt<8;++mt) dh[mt] = (f32x4){0.f,0.f,0.f,0.f};
    gemmT8(pW1, 16, half*8, tile, row, l, dh);
    #pragma unroll
    for(int mt=0;mt<8;++mt){
      int feat = half*128 + mt*16 + g*4;
      float4 bb = *(const float4*)(b1p + feat);
      float h0 = fmaxf(dh[mt][0]+bb.x, 0.f);
      float h1 = fmaxf(dh[mt][1]+bb.y, 0.f);
      float h2 = fmaxf(dh[mt][2]+bb.z, 0.f);
      float h3 = fmaxf(dh[mt][3]+bb.w, 0.f);
      uint2 o; o.x = packbf(h0,h1); o.y = packbf(h2,h3);
      *(uint2*)&htile[swz128(row, feat>>1)] = o;
    }
  }
  __syncthreads();
  // FFN layer 2 (K=256) + residual
  f32x4 oacc[8];
  #pragma unroll
  for(int mt=0;mt<8;++mt) oacc[mt] = (f32x4){0.f,0.f,0.f,0.f};
  gemmT8_k256(pW2, htile, row, l, oacc);
  if (valid){
    #pragma unroll
    for(int mt=0;mt<8;++mt){
      float4 bb = *(const float4*)(b2p + mt*16 + g*4);
      float4 o;
      o.x = xm[mt][0] + oacc[mt][0] + bb.x;
      o.y = xm[mt][1] + oacc[mt][1] + bb.y;
      o.z = xm[mt][2] + oacc[mt][2] + bb.z;
      o.w = xm[mt][3] + oacc[mt][3] + bb.w;
      *(float4*)(xout + node*128 + mt*16 + g*4) = o;
    }
  }
}

extern "C" void kernel_launch(void* const* d_in, const int* in_sizes, int n_in,
                              void* d_out, int out_size, void* d_ws, size_t ws_size,
                              hipStream_t stream) {
  (void)in_sizes; (void)n_in; (void)out_size; (void)ws_size;
  const float* xin = (const float*)d_in[0];
  const float* ein = (const float*)d_in[1];
  const float* Wq = (const float*)d_in[2];  const float* bq = (const float*)d_in[3];
  const float* Wk = (const float*)d_in[4];  const float* bk = (const float*)d_in[5];
  const float* Wv = (const float*)d_in[6];  const float* bv = (const float*)d_in[7];
  const float* We = (const float*)d_in[8];  const float* be = (const float*)d_in[9];
  const float* Wg = (const float*)d_in[10]; const float* bg = (const float*)d_in[11];
  const float* Wo = (const float*)d_in[12]; const float* bo = (const float*)d_in[13];
  const float* Woe= (const float*)d_in[14]; const float* boe= (const float*)d_in[15];
  const float* l1g= (const float*)d_in[16]; const float* l1b= (const float*)d_in[17];
  const float* l1eg=(const float*)d_in[18]; const float* l1eb=(const float*)d_in[19];
  const float* l2g= (const float*)d_in[20]; const float* l2b= (const float*)d_in[21];
  const float* W1 = (const float*)d_in[22]; const float* b1 = (const float*)d_in[23];
  const float* W2 = (const float*)d_in[24]; const float* b2 = (const float*)d_in[25];
  const int* eidx = (const int*)d_in[26];

  float* xout = (float*)d_out;
  float* eout = xout + (size_t)NN*128;

  // ws: esc [NE*8 f32] | gv [NE*64 u32] | qv,kv,vv [NN*64 u32] | xattnb [NN*64 u32]
  //     | deg,starts,cursor [NN] | perm [NE] | packed W (bf16)
  float* escp = (float*)d_ws;
  u32* gvp = (u32*)(escp + (size_t)NE*8);
  u32* qv = gvp + (size_t)NE*64;
  u32* kv = qv + (size_t)NN*64;
  u32* vv = kv + (size_t)NN*64;
  u32* xattnb = vv + (size_t)NN*64;
  int* deg = (int*)(xattnb + (size_t)NN*64);
  int* starts = deg + NN;
  int* cursor = starts + NN;
  int* perm = cursor + NN;
  u16* pw  = (u16*)(perm + NE);
  u16* pWq = pw;            u16* pWk = pWq + 16384;  u16* pWv = pWk + 16384;
  u16* pWe = pWv + 16384;   u16* pWg = pWe + 16384;  u16* pWoe= pWg + 16384;
  u16* pWo = pWoe + 16384;  u16* pW1 = pWo + 16384;  u16* pW2 = pW1 + 32768;

  k_packall<<<(7*16384+65536+255)/256, 256, 0, stream>>>(Wq,Wk,Wv,We,Wg,Woe,Wo,W1,W2, pw);

  // CSR build
  hipMemsetAsync(deg, 0, NN*sizeof(int), stream);
  k_deg<<<(NE+255)/256, 256, 0, stream>>>(eidx, deg);
  k_scan<<<1, 1024, 0, stream>>>(deg, starts, cursor);
  k_scatter<<<(NE+255)/256, 256, 0, stream>>>(eidx, cursor, perm);

  k_qkv<<<(NN+63)/64, 256, 0, stream>>>(xin, l1g, l1b, pWq, bq, pWk, bk, pWv, bv, qv, kv, vv);
  k_edge<<<NE/64, 256, 0, stream>>>(ein, l1eg, l1eb, pWg, bg, pWe, be, pWoe, boe,
                                    eidx, perm, qv, kv, vv, gvp, escp, eout);
  k_agg<<<(NN+3)/4, 256, 0, stream>>>(gvp, escp, starts, cursor, xattnb);
  k_out<<<(NN+63)/64, 256, 0, stream>>>(xin, xattnb, pWo, bo, l2g, l2b,
                                        pW1, b1, pW2, b2, xout);
}

// Round 7
// 735.594 us; speedup vs baseline: 1.1275x; 1.1022x over previous
//
#include <hip/hip_runtime.h>

#define NN 50000
#define NE 400000

typedef unsigned int u32;
typedef unsigned short u16;
typedef __attribute__((ext_vector_type(8))) short short8; // 8 bf16 = 4 VGPR
typedef __attribute__((ext_vector_type(4))) float f32x4;

union FragU { uint4 u; short8 s; };
union Chunk { uint4 v[4]; u32 d[16]; };

__device__ __forceinline__ float bflo(u32 w){ union{u32 i; float f;} v; v.i = w<<16; return v.f; }
__device__ __forceinline__ float bfhi(u32 w){ union{u32 i; float f;} v; v.i = w & 0xffff0000u; return v.f; }
__device__ __forceinline__ u32 packbf(float a, float b){
  union{float f;u32 i;} x, y; x.f=a; y.f=b;
  u32 xi = x.i + (((x.i>>16)&1u) + 0x7fffu);
  u32 yi = y.i + (((y.i>>16)&1u) + 0x7fffu);
  return (xi>>16) | (yi & 0xffff0000u);
}

// swizzled dword index in a [rows][128]-bf16 tile (64 u32/row)
__device__ __forceinline__ int swz64(int row, int cp){ return row*64 + (cp ^ ((row&7)<<2)); }
// same for [rows][256]-bf16 tile (128 u32/row)
__device__ __forceinline__ int swz128(int row, int cp){ return row*128 + (cp ^ ((row&7)<<2)); }

// Stage 64 rows (f32, stride 128) with LayerNorm -> bf16 swizzled tile. 4 threads/row.
__device__ __forceinline__ void stage_ln(const float* __restrict__ src, long base, long nrows,
                                         const float* __restrict__ gam, const float* __restrict__ bet,
                                         u32* __restrict__ tile, int t)
{
  int row = t>>2, sub = t&3;
  bool valid = (base + row) < nrows;
  const float* p = src + (base+row)*128 + sub*32;
  float4 x[8];
  float s=0.f, s2=0.f;
  #pragma unroll
  for(int q=0;q<8;++q){
    x[q] = valid ? *(const float4*)(p + 4*q) : make_float4(0.f,0.f,0.f,0.f);
    s  += x[q].x + x[q].y + x[q].z + x[q].w;
    s2 += x[q].x*x[q].x + x[q].y*x[q].y + x[q].z*x[q].z + x[q].w*x[q].w;
  }
  s  += __shfl_xor(s,1);  s  += __shfl_xor(s,2);
  s2 += __shfl_xor(s2,1); s2 += __shfl_xor(s2,2);
  float mu  = s*(1.f/128.f);
  float var = fmaxf(s2*(1.f/128.f) - mu*mu, 0.f);
  float rs  = rsqrtf(var + 1e-5f);
  const float* gp = gam + sub*32; const float* bp = bet + sub*32;
  #pragma unroll
  for(int m4=0;m4<4;++m4){
    float4 g0 = *(const float4*)(gp + 8*m4);
    float4 g1 = *(const float4*)(gp + 8*m4 + 4);
    float4 b0 = *(const float4*)(bp + 8*m4);
    float4 b1 = *(const float4*)(bp + 8*m4 + 4);
    float4 xa = x[2*m4], xb = x[2*m4+1];
    uint4 wv;
    wv.x = packbf((xa.x-mu)*rs*g0.x+b0.x, (xa.y-mu)*rs*g0.y+b0.y);
    wv.y = packbf((xa.z-mu)*rs*g0.z+b0.z, (xa.w-mu)*rs*g0.w+b0.w);
    wv.z = packbf((xb.x-mu)*rs*g1.x+b1.x, (xb.y-mu)*rs*g1.y+b1.y);
    wv.w = packbf((xb.z-mu)*rs*g1.z+b1.z, (xb.w-mu)*rs*g1.w+b1.w);
    *(uint4*)&tile[swz64(row, sub*16 + m4*4)] = wv;
  }
}

// D^T = W^T (A-op, packed PW) x data (B-op from swizzled tile). 8 mt tiles, K=128.
__device__ __forceinline__ void gemmT8(const u16* __restrict__ PW, int NT, int mtoff,
                                       const u32* __restrict__ tile, int row, int l,
                                       f32x4 acc[8])
{
  int g = l>>4;
  #pragma unroll
  for(int kc=0;kc<4;++kc){
    FragU bf; bf.u = *(const uint4*)&tile[swz64(row, kc*16 + g*4)];
    #pragma unroll
    for(int mt=0;mt<8;++mt){
      FragU af; af.u = ((const uint4*)PW)[(size_t)(kc*NT + mtoff + mt)*64 + l];
      acc[mt] = __builtin_amdgcn_mfma_f32_16x16x32_bf16(af.s, bf.s, acc[mt], 0,0,0);
    }
  }
}

// K=256 variant (8 kc) reading from [64][256] tile
__device__ __forceinline__ void gemmT8_k256(const u16* __restrict__ PW,
                                            const u32* __restrict__ tile, int row, int l,
                                            f32x4 acc[8])
{
  int g = l>>4;
  #pragma unroll
  for(int kc=0;kc<8;++kc){
    FragU bf; bf.u = *(const uint4*)&tile[swz128(row, kc*16 + g*4)];
    #pragma unroll
    for(int mt=0;mt<8;++mt){
      FragU af; af.u = ((const uint4*)PW)[(size_t)(kc*8 + mt)*64 + l];
      acc[mt] = __builtin_amdgcn_mfma_f32_16x16x32_bf16(af.s, bf.s, acc[mt], 0,0,0);
    }
  }
}

// Pack all 9 f32 weights into MFMA A-fragment order (bf16), one launch.
__global__ __launch_bounds__(256)
void k_packall(const float* __restrict__ Wq, const float* __restrict__ Wk,
               const float* __restrict__ Wv, const float* __restrict__ We,
               const float* __restrict__ Wg, const float* __restrict__ Woe,
               const float* __restrict__ Wo, const float* __restrict__ W1,
               const float* __restrict__ W2, u16* __restrict__ dst)
{
  int i = blockIdx.x*256 + threadIdx.x;
  const float* src; int N, idx;
  if (i < 7*16384){
    int m = i >> 14; idx = i & 16383; N=128;
    src = (m==0)?Wq:(m==1)?Wk:(m==2)?Wv:(m==3)?We:(m==4)?Wg:(m==5)?Woe:Wo;
  } else if (i < 7*16384 + 32768){ idx = i - 7*16384; N=256; src = W1; }
  else if (i < 7*16384 + 65536){ idx = i - 7*16384 - 32768; N=128; src = W2; }
  else return;
  int j = idx & 7, l = (idx>>3) & 63;
  int rest = idx >> 9;
  int NT = N >> 4;
  int nt = rest % NT, kc = rest / NT;
  int k = kc*32 + (l>>4)*8 + j;
  int n = nt*16 + (l&15);
  union{float f;u32 u;} x; x.f = src[(size_t)k*N + n];
  dst[i] = (u16)((x.u + (((x.u>>16)&1u) + 0x7fffu)) >> 16);
}

// ---------------- CSR build ----------------
__global__ __launch_bounds__(256)
void k_deg(const int* __restrict__ eidx, int* __restrict__ deg){
  int e = blockIdx.x*256 + threadIdx.x;
  if (e < NE) atomicAdd(&deg[eidx[NE+e]], 1);
}

__global__ __launch_bounds__(1024)
void k_scan(const int* __restrict__ deg, int* __restrict__ starts, int* __restrict__ cursor){
  __shared__ int part[1024];
  int t = threadIdx.x;
  const int CH = (NN + 1023)/1024;
  int base = t*CH;
  int s = 0;
  for (int i=0;i<CH;++i){ int idx = base+i; if (idx < NN) s += deg[idx]; }
  part[t] = s; __syncthreads();
  for (int off=1; off<1024; off<<=1){
    int v = (t>=off) ? part[t-off] : 0;
    __syncthreads();
    part[t] += v;
    __syncthreads();
  }
  int pre = (t==0) ? 0 : part[t-1];
  for (int i=0;i<CH;++i){
    int idx = base+i;
    if (idx < NN){ starts[idx]=pre; cursor[idx]=pre; pre += deg[idx]; }
  }
}

__global__ __launch_bounds__(256)
void k_scatter(const int* __restrict__ eidx, int* __restrict__ cursor, int* __restrict__ elist){
  int e = blockIdx.x*256 + threadIdx.x;
  if (e < NE){
    int d = eidx[NE+e];
    int pos = atomicAdd(&cursor[d], 1);
    elist[pos] = e;
  }
}

// ---------------- K1: node LN + q,k,v projections (plain packed-pair rows) ----------
__global__ __launch_bounds__(256)
void k_qkv(const float* __restrict__ xin,
           const float* __restrict__ l1g, const float* __restrict__ l1b,
           const u16* __restrict__ pWq, const float* __restrict__ bq,
           const u16* __restrict__ pWk, const float* __restrict__ bk,
           const u16* __restrict__ pWv, const float* __restrict__ bv,
           u32* __restrict__ qv, u32* __restrict__ kv, u32* __restrict__ vv)
{
  __shared__ u32 tile[64*64];
  int t = threadIdx.x;
  long base = (long)blockIdx.x * 64;
  stage_ln(xin, base, NN, l1g, l1b, tile, t);
  __syncthreads();
  int w = t>>6, l = t&63, g = l>>4;
  int row = w*16 + (l&15);
  long node = base + row;
  bool valid = node < NN;

  f32x4 acc[8];
  const u16* pws[3] = {pWq, pWk, pWv};
  const float* bbs[3] = {bq, bk, bv};
  u32* outs[3] = {qv, kv, vv};
  #pragma unroll
  for(int s3=0;s3<3;++s3){
    #pragma unroll
    for(int mt=0;mt<8;++mt) acc[mt] = (f32x4){0.f,0.f,0.f,0.f};
    gemmT8(pws[s3], 8, 0, tile, row, l, acc);
    if (valid){
      u32* op = outs[s3] + node*64;
      #pragma unroll
      for(int mt=0;mt<8;++mt){
        float4 bb = *(const float4*)(bbs[s3] + mt*16 + g*4);
        uint2 o;
        o.x = packbf(acc[mt][0]+bb.x, acc[mt][1]+bb.y);
        o.y = packbf(acc[mt][2]+bb.z, acc[mt][3]+bb.w);
        *(uint2*)(op + mt*8 + g*2) = o;
      }
    }
  }
}

// ---------------- K1b: high-occupancy random gather: qk = q[dst] (x) k[src] --------
// 16 lanes/edge, no LDS, tiny VGPR -> full occupancy hides L3 latency via TLP.
__global__ __launch_bounds__(256)
void k_gather(const int* __restrict__ eidx,
              const u32* __restrict__ qv, const u32* __restrict__ kv,
              u32* __restrict__ qkp)
{
  int t = blockIdx.x*256 + threadIdx.x;
  int e = t >> 4;
  int il = t & 15;
  if (e >= NE) return;
  int s_ = eidx[e], d_ = eidx[NE + e];
  uint4 q = *(const uint4*)(qv + (size_t)d_*64 + il*4);
  uint4 k = *(const uint4*)(kv + (size_t)s_*64 + il*4);
  uint4 o;
  o.x = packbf(bflo(q.x)*bflo(k.x), bfhi(q.x)*bfhi(k.x));
  o.y = packbf(bflo(q.y)*bflo(k.y), bfhi(q.y)*bfhi(k.y));
  o.z = packbf(bflo(q.z)*bflo(k.z), bfhi(q.z)*bfhi(k.z));
  o.w = packbf(bflo(q.w)*bflo(k.w), bfhi(q.w)*bfhi(k.w));
  *(uint4*)(qkp + (size_t)e*64 + il*4) = o;
}

// ---------------- K2: fused edge pass (round-4 structure, sequential qk) -----------
__global__ __launch_bounds__(256)
void k_edge(const float* __restrict__ ein,
            const float* __restrict__ l1eg, const float* __restrict__ l1eb,
            const u16* __restrict__ pWg, const float* __restrict__ bg,
            const u16* __restrict__ pWe, const float* __restrict__ be,
            const u16* __restrict__ pWoe, const float* __restrict__ boe,
            const int* __restrict__ eidx,
            const u32* __restrict__ qkp, const u32* __restrict__ vv,
            u32* __restrict__ gvp, float* __restrict__ escp,
            float* __restrict__ eout)
{
  __shared__ u32 tile[64*64];
  int t = threadIdx.x;
  long base = (long)blockIdx.x * 64;
  stage_ln(ein, base, NE, l1eg, l1eb, tile, t);
  __syncthreads();
  int w = t>>6, l = t&63, g = l>>4;
  int row = w*16 + (l&15);
  long edge = base + row;
  int s_ = eidx[edge];
  const u32* qkrow = qkp + (size_t)edge*64;
  const u32* vrow  = vv  + (size_t)s_*64;

  f32x4 acc[8], gate[8];
  // gate = sigmoid(LN(e)@Wg + bg)
  #pragma unroll
  for(int mt=0;mt<8;++mt) acc[mt] = (f32x4){0.f,0.f,0.f,0.f};
  gemmT8(pWg, 8, 0, tile, row, l, acc);
  #pragma unroll
  for(int mt=0;mt<8;++mt){
    float4 bb = *(const float4*)(bg + mt*16 + g*4);
    gate[mt][0] = 1.f/(1.f+__expf(-(acc[mt][0]+bb.x)));
    gate[mt][1] = 1.f/(1.f+__expf(-(acc[mt][1]+bb.y)));
    gate[mt][2] = 1.f/(1.f+__expf(-(acc[mt][2]+bb.z)));
    gate[mt][3] = 1.f/(1.f+__expf(-(acc[mt][3]+bb.w)));
  }
  // s_elt = LN(e)@We + be + qk (pre-gathered, sequential); scores -> esc
  #pragma unroll
  for(int mt=0;mt<8;++mt) acc[mt] = (f32x4){0.f,0.f,0.f,0.f};
  gemmT8(pWe, 8, 0, tile, row, l, acc);
  float esc[8];
  #pragma unroll
  for(int mt=0;mt<8;++mt){
    float4 bb = *(const float4*)(be + mt*16 + g*4);
    uint2 qk = *(const uint2*)(qkrow + mt*8 + g*2);
    acc[mt][0] += bb.x + bflo(qk.x);
    acc[mt][1] += bb.y + bfhi(qk.x);
    acc[mt][2] += bb.z + bflo(qk.y);
    acc[mt][3] += bb.w + bfhi(qk.y);
    float ps = acc[mt][0]+acc[mt][1]+acc[mt][2]+acc[mt][3];
    ps += __shfl_xor(ps, 16);
    ps += __shfl_xor(ps, 32);                  // sum over all 16 feats of head mt
    float sc = fminf(fmaxf(ps*0.25f, -5.f), 5.f);
    esc[mt] = __expf(sc);                      // clipped => no max-subtract needed
  }
  // store esc [edge][8] f32 (one lane per edge)
  if (g==0){
    float4 e0 = {esc[0],esc[1],esc[2],esc[3]};
    float4 e1 = {esc[4],esc[5],esc[6],esc[7]};
    *(float4*)(escp + (size_t)edge*8)     = e0;
    *(float4*)(escp + (size_t)edge*8 + 4) = e1;
  }
  // numerator input: gv = gate (x) v[src]  (bf16, edge order)
  #pragma unroll
  for(int mt=0;mt<8;++mt){
    uint2 vw = *(const uint2*)(vrow + mt*8 + g*2);
    uint2 o;
    o.x = packbf(gate[mt][0]*bflo(vw.x), gate[mt][1]*bfhi(vw.x));
    o.y = packbf(gate[mt][2]*bflo(vw.y), gate[mt][3]*bfhi(vw.y));
    *(uint2*)(gvp + (size_t)edge*64 + mt*8 + g*2) = o;
  }
  __syncthreads();                 // all waves done reading LN tile
  // write s_elt (bf16) into tile (B-layout for Woe GEMM)
  #pragma unroll
  for(int mt=0;mt<8;++mt){
    uint2 o;
    o.x = packbf(acc[mt][0], acc[mt][1]);
    o.y = packbf(acc[mt][2], acc[mt][3]);
    *(uint2*)&tile[swz64(row, mt*8 + g*2)] = o;
  }
  __syncthreads();
  // e_out = e_in + s_elt@Woe + boe
  f32x4 oacc[8];
  #pragma unroll
  for(int mt=0;mt<8;++mt) oacc[mt] = (f32x4){0.f,0.f,0.f,0.f};
  gemmT8(pWoe, 8, 0, tile, row, l, oacc);
  #pragma unroll
  for(int mt=0;mt<8;++mt){
    float4 bb = *(const float4*)(boe + mt*16 + g*4);
    float4 er = *(const float4*)(ein + edge*128 + mt*16 + g*4);
    float4 o;
    o.x = er.x + oacc[mt][0] + bb.x;
    o.y = er.y + oacc[mt][1] + bb.y;
    o.z = er.z + oacc[mt][2] + bb.z;
    o.w = er.w + oacc[mt][3] + bb.w;
    *(float4*)(eout + edge*128 + mt*16 + g*4) = o;
  }
}

// ---------------- K2b: per-node aggregation over CSR (elist), packed output --------
__global__ __launch_bounds__(256)
void k_agg(const u32* __restrict__ gvp, const float* __restrict__ escp,
           const int* __restrict__ elist, const int* __restrict__ starts,
           const int* __restrict__ ends, u32* __restrict__ xattnb)
{
  int w = threadIdx.x>>6, l = threadIdx.x&63;
  long n = (long)blockIdx.x*4 + w;
  if (n >= NN) return;
  int h = l>>3;                       // head for feats 2l,2l+1
  int s = starts[n], e = ends[n];
  float s0=0.f, s1=0.f, den=0.f;
  for (int i=s;i<e;++i){
    int ed = elist[i];
    u32 gvw = gvp[(size_t)ed*64 + l];
    float a = escp[(size_t)ed*8 + h];
    s0 += a*bflo(gvw);
    s1 += a*bfhi(gvw);
    den += a;
  }
  float inv = den>0.f ? 1.f/den : 0.f;  // zero in-degree -> 0 (segment_sum semantics)
  xattnb[n*64 + l] = packbf(s0*inv, s1*inv);
}

// ---------------- K3: node epilogue: Wo, LN2, FFN ----------------
__global__ __launch_bounds__(256)
void k_out(const float* __restrict__ xin,
           const u32* __restrict__ xattnb,
           const u16* __restrict__ pWo, const float* __restrict__ bo,
           const float* __restrict__ l2g, const float* __restrict__ l2b,
           const u16* __restrict__ pW1, const float* __restrict__ b1p,
           const u16* __restrict__ pW2, const float* __restrict__ b2p,
           float* __restrict__ xout)
{
  __shared__ u32 tile[64*64];
  __shared__ u32 htile[64*128];
  int t = threadIdx.x;
  long base = (long)blockIdx.x * 64;
  // stage attention output (packed bf16, plain rows) -> swizzled tile (same dword map)
  {
    int row = t>>2, sub = t&3;
    long node = base + row;
    bool valid = node < NN;
    Chunk c;
    if (valid){
      const uint4* p = (const uint4*)(xattnb + node*64 + sub*16);
      #pragma unroll
      for(int i=0;i<4;++i) c.v[i] = p[i];
    } else {
      #pragma unroll
      for(int i=0;i<16;++i) c.d[i] = 0;
    }
    #pragma unroll
    for(int i=0;i<4;++i)
      *(uint4*)&tile[swz64(row, sub*16 + i*4)] = c.v[i];
  }
  __syncthreads();
  int w = t>>6, l = t&63, g = l>>4;
  int row = w*16 + (l&15);
  long node = base + row;
  bool valid = node < NN;

  // Wo GEMM; xmid = x_in + out@Wo + bo
  f32x4 acc[8], xm[8];
  #pragma unroll
  for(int mt=0;mt<8;++mt) acc[mt] = (f32x4){0.f,0.f,0.f,0.f};
  gemmT8(pWo, 8, 0, tile, row, l, acc);
  #pragma unroll
  for(int mt=0;mt<8;++mt){
    float4 bb = *(const float4*)(bo + mt*16 + g*4);
    float4 xr = valid ? *(const float4*)(xin + node*128 + mt*16 + g*4) : make_float4(0.f,0.f,0.f,0.f);
    xm[mt][0] = xr.x + acc[mt][0] + bb.x;
    xm[mt][1] = xr.y + acc[mt][1] + bb.y;
    xm[mt][2] = xr.z + acc[mt][2] + bb.z;
    xm[mt][3] = xr.w + acc[mt][3] + bb.w;
  }
  // LN2 in-register
  float s=0.f, s2=0.f;
  #pragma unroll
  for(int mt=0;mt<8;++mt){
    s  += xm[mt][0]+xm[mt][1]+xm[mt][2]+xm[mt][3];
    s2 += xm[mt][0]*xm[mt][0]+xm[mt][1]*xm[mt][1]+xm[mt][2]*xm[mt][2]+xm[mt][3]*xm[mt][3];
  }
  s  += __shfl_xor(s,16);  s  += __shfl_xor(s,32);
  s2 += __shfl_xor(s2,16); s2 += __shfl_xor(s2,32);
  float mu  = s*(1.f/128.f);
  float var = fmaxf(s2*(1.f/128.f) - mu*mu, 0.f);
  float rs  = rsqrtf(var + 1e-5f);
  __syncthreads();              // done reading tile (Wo B-frags)
  #pragma unroll
  for(int mt=0;mt<8;++mt){
    float4 gg = *(const float4*)(l2g + mt*16 + g*4);
    float4 bb = *(const float4*)(l2b + mt*16 + g*4);
    float h0 = (xm[mt][0]-mu)*rs*gg.x + bb.x;
    float h1 = (xm[mt][1]-mu)*rs*gg.y + bb.y;
    float h2 = (xm[mt][2]-mu)*rs*gg.z + bb.z;
    float h3 = (xm[mt][3]-mu)*rs*gg.w + bb.w;
    uint2 o; o.x = packbf(h0,h1); o.y = packbf(h2,h3);
    *(uint2*)&tile[swz64(row, mt*8 + g*2)] = o;
  }
  __syncthreads();
  // FFN layer 1 (256 outs in two halves), relu -> htile
  #pragma unroll
  for(int half=0; half<2; ++half){
    f32x4 dh[8];
    #pragma unroll
    for(int mt=0;mt<8;++mt) dh[mt] = (f32x4){0.f,0.f,0.f,0.f};
    gemmT8(pW1, 16, half*8, tile, row, l, dh);
    #pragma unroll
    for(int mt=0;mt<8;++mt){
      int feat = half*128 + mt*16 + g*4;
      float4 bb = *(const float4*)(b1p + feat);
      float h0 = fmaxf(dh[mt][0]+bb.x, 0.f);
      float h1 = fmaxf(dh[mt][1]+bb.y, 0.f);
      float h2 = fmaxf(dh[mt][2]+bb.z, 0.f);
      float h3 = fmaxf(dh[mt][3]+bb.w, 0.f);
      uint2 o; o.x = packbf(h0,h1); o.y = packbf(h2,h3);
      *(uint2*)&htile[swz128(row, feat>>1)] = o;
    }
  }
  __syncthreads();
  // FFN layer 2 (K=256) + residual
  f32x4 oacc[8];
  #pragma unroll
  for(int mt=0;mt<8;++mt) oacc[mt] = (f32x4){0.f,0.f,0.f,0.f};
  gemmT8_k256(pW2, htile, row, l, oacc);
  if (valid){
    #pragma unroll
    for(int mt=0;mt<8;++mt){
      float4 bb = *(const float4*)(b2p + mt*16 + g*4);
      float4 o;
      o.x = xm[mt][0] + oacc[mt][0] + bb.x;
      o.y = xm[mt][1] + oacc[mt][1] + bb.y;
      o.z = xm[mt][2] + oacc[mt][2] + bb.z;
      o.w = xm[mt][3] + oacc[mt][3] + bb.w;
      *(float4*)(xout + node*128 + mt*16 + g*4) = o;
    }
  }
}

extern "C" void kernel_launch(void* const* d_in, const int* in_sizes, int n_in,
                              void* d_out, int out_size, void* d_ws, size_t ws_size,
                              hipStream_t stream) {
  (void)in_sizes; (void)n_in; (void)out_size; (void)ws_size;
  const float* xin = (const float*)d_in[0];
  const float* ein = (const float*)d_in[1];
  const float* Wq = (const float*)d_in[2];  const float* bq = (const float*)d_in[3];
  const float* Wk = (const float*)d_in[4];  const float* bk = (const float*)d_in[5];
  const float* Wv = (const float*)d_in[6];  const float* bv = (const float*)d_in[7];
  const float* We = (const float*)d_in[8];  const float* be = (const float*)d_in[9];
  const float* Wg = (const float*)d_in[10]; const float* bg = (const float*)d_in[11];
  const float* Wo = (const float*)d_in[12]; const float* bo = (const float*)d_in[13];
  const float* Woe= (const float*)d_in[14]; const float* boe= (const float*)d_in[15];
  const float* l1g= (const float*)d_in[16]; const float* l1b= (const float*)d_in[17];
  const float* l1eg=(const float*)d_in[18]; const float* l1eb=(const float*)d_in[19];
  const float* l2g= (const float*)d_in[20]; const float* l2b= (const float*)d_in[21];
  const float* W1 = (const float*)d_in[22]; const float* b1 = (const float*)d_in[23];
  const float* W2 = (const float*)d_in[24]; const float* b2 = (const float*)d_in[25];
  const int* eidx = (const int*)d_in[26];

  float* xout = (float*)d_out;
  float* eout = xout + (size_t)NN*128;

  // ws: esc [NE*8 f32] | gv [NE*64 u32] | qk [NE*64 u32] | qv,kv,vv [NN*64 u32]
  //     | xattnb [NN*64 u32] | deg,starts,cursor [NN] | elist [NE] | packed W (bf16)
  float* escp = (float*)d_ws;
  u32* gvp = (u32*)(escp + (size_t)NE*8);
  u32* qkp = gvp + (size_t)NE*64;
  u32* qv = qkp + (size_t)NE*64;
  u32* kv = qv + (size_t)NN*64;
  u32* vv = kv + (size_t)NN*64;
  u32* xattnb = vv + (size_t)NN*64;
  int* deg = (int*)(xattnb + (size_t)NN*64);
  int* starts = deg + NN;
  int* cursor = starts + NN;
  int* elist = cursor + NN;
  u16* pw  = (u16*)(elist + NE);
  u16* pWq = pw;            u16* pWk = pWq + 16384;  u16* pWv = pWk + 16384;
  u16* pWe = pWv + 16384;   u16* pWg = pWe + 16384;  u16* pWoe= pWg + 16384;
  u16* pWo = pWoe + 16384;  u16* pW1 = pWo + 16384;  u16* pW2 = pW1 + 32768;

  k_packall<<<(7*16384+65536+255)/256, 256, 0, stream>>>(Wq,Wk,Wv,We,Wg,Woe,Wo,W1,W2, pw);

  // CSR build
  hipMemsetAsync(deg, 0, NN*sizeof(int), stream);
  k_deg<<<(NE+255)/256, 256, 0, stream>>>(eidx, deg);
  k_scan<<<1, 1024, 0, stream>>>(deg, starts, cursor);
  k_scatter<<<(NE+255)/256, 256, 0, stream>>>(eidx, cursor, elist);

  k_qkv<<<(NN+63)/64, 256, 0, stream>>>(xin, l1g, l1b, pWq, bq, pWk, bk, pWv, bv, qv, kv, vv);
  k_gather<<<(NE*16)/256, 256, 0, stream>>>(eidx, qv, kv, qkp);
  k_edge<<<NE/64, 256, 0, stream>>>(ein, l1eg, l1eb, pWg, bg, pWe, be, pWoe, boe,
                                    eidx, qkp, vv, gvp, escp, eout);
  k_agg<<<(NN+3)/4, 256, 0, stream>>>(gvp, escp, elist, starts, cursor, xattnb);
  k_out<<<(NN+63)/64, 256, 0, stream>>>(xin, xattnb, pWo, bo, l2g, l2b,
                                        pW1, b1, pW2, b2, xout);
}

// Round 8
// 678.877 us; speedup vs baseline: 1.2217x; 1.0835x over previous
//
#include <hip/hip_runtime.h>

#define NN 50000
#define NE 400000

typedef unsigned int u32;
typedef unsigned short u16;
typedef __attribute__((ext_vector_type(8))) short short8; // 8 bf16 = 4 VGPR
typedef __attribute__((ext_vector_type(4))) float f32x4;

union FragU { uint4 u; short8 s; };
union Chunk { uint4 v[4]; u32 d[16]; };

__device__ __forceinline__ float bflo(u32 w){ union{u32 i; float f;} v; v.i = w<<16; return v.f; }
__device__ __forceinline__ float bfhi(u32 w){ union{u32 i; float f;} v; v.i = w & 0xffff0000u; return v.f; }
__device__ __forceinline__ u32 packbf(float a, float b){
  union{float f;u32 i;} x, y; x.f=a; y.f=b;
  u32 xi = x.i + (((x.i>>16)&1u) + 0x7fffu);
  u32 yi = y.i + (((y.i>>16)&1u) + 0x7fffu);
  return (xi>>16) | (yi & 0xffff0000u);
}

// swizzled dword index in a [rows][128]-bf16 tile (64 u32/row)
__device__ __forceinline__ int swz64(int row, int cp){ return row*64 + (cp ^ ((row&7)<<2)); }
// same for [rows][256]-bf16 tile (128 u32/row)
__device__ __forceinline__ int swz128(int row, int cp){ return row*128 + (cp ^ ((row&7)<<2)); }

// Stage 64 rows with LayerNorm -> bf16 swizzled tile. 4 threads/row (256-thread blocks).
__device__ __forceinline__ void stage_ln(const float* __restrict__ src, long base, long nrows,
                                         const float* __restrict__ gam, const float* __restrict__ bet,
                                         u32* __restrict__ tile, int t)
{
  int row = t>>2, sub = t&3;
  bool valid = (base + row) < nrows;
  const float* p = src + (base+row)*128 + sub*32;
  float4 x[8];
  float s=0.f, s2=0.f;
  #pragma unroll
  for(int q=0;q<8;++q){
    x[q] = valid ? *(const float4*)(p + 4*q) : make_float4(0.f,0.f,0.f,0.f);
    s  += x[q].x + x[q].y + x[q].z + x[q].w;
    s2 += x[q].x*x[q].x + x[q].y*x[q].y + x[q].z*x[q].z + x[q].w*x[q].w;
  }
  s  += __shfl_xor(s,1);  s  += __shfl_xor(s,2);
  s2 += __shfl_xor(s2,1); s2 += __shfl_xor(s2,2);
  float mu  = s*(1.f/128.f);
  float var = fmaxf(s2*(1.f/128.f) - mu*mu, 0.f);
  float rs  = rsqrtf(var + 1e-5f);
  const float* gp = gam + sub*32; const float* bp = bet + sub*32;
  #pragma unroll
  for(int m4=0;m4<4;++m4){
    float4 g0 = *(const float4*)(gp + 8*m4);
    float4 g1 = *(const float4*)(gp + 8*m4 + 4);
    float4 b0 = *(const float4*)(bp + 8*m4);
    float4 b1 = *(const float4*)(bp + 8*m4 + 4);
    float4 xa = x[2*m4], xb = x[2*m4+1];
    uint4 wv;
    wv.x = packbf((xa.x-mu)*rs*g0.x+b0.x, (xa.y-mu)*rs*g0.y+b0.y);
    wv.y = packbf((xa.z-mu)*rs*g0.z+b0.z, (xa.w-mu)*rs*g0.w+b0.w);
    wv.z = packbf((xb.x-mu)*rs*g1.x+b1.x, (xb.y-mu)*rs*g1.y+b1.y);
    wv.w = packbf((xb.z-mu)*rs*g1.z+b1.z, (xb.w-mu)*rs*g1.w+b1.w);
    *(uint4*)&tile[swz64(row, sub*16 + m4*4)] = wv;
  }
}

// Stage variant for 512-thread blocks: 8 threads/row, no bounds check (NE % 64 == 0).
__device__ __forceinline__ void stage_ln8(const float* __restrict__ src, long base,
                                          const float* __restrict__ gam, const float* __restrict__ bet,
                                          u32* __restrict__ tile, int t)
{
  int row = t>>3, sub = t&7;
  const float* p = src + (base+row)*128 + sub*16;
  float4 x[4];
  float s=0.f, s2=0.f;
  #pragma unroll
  for(int q=0;q<4;++q){
    x[q] = *(const float4*)(p + 4*q);
    s  += x[q].x + x[q].y + x[q].z + x[q].w;
    s2 += x[q].x*x[q].x + x[q].y*x[q].y + x[q].z*x[q].z + x[q].w*x[q].w;
  }
  s  += __shfl_xor(s,1);  s  += __shfl_xor(s,2);  s  += __shfl_xor(s,4);
  s2 += __shfl_xor(s2,1); s2 += __shfl_xor(s2,2); s2 += __shfl_xor(s2,4);
  float mu  = s*(1.f/128.f);
  float var = fmaxf(s2*(1.f/128.f) - mu*mu, 0.f);
  float rs  = rsqrtf(var + 1e-5f);
  const float* gp = gam + sub*16; const float* bp = bet + sub*16;
  #pragma unroll
  for(int m4=0;m4<2;++m4){
    float4 g0 = *(const float4*)(gp + 8*m4);
    float4 g1 = *(const float4*)(gp + 8*m4 + 4);
    float4 b0 = *(const float4*)(bp + 8*m4);
    float4 b1 = *(const float4*)(bp + 8*m4 + 4);
    float4 xa = x[2*m4], xb = x[2*m4+1];
    uint4 wv;
    wv.x = packbf((xa.x-mu)*rs*g0.x+b0.x, (xa.y-mu)*rs*g0.y+b0.y);
    wv.y = packbf((xa.z-mu)*rs*g0.z+b0.z, (xa.w-mu)*rs*g0.w+b0.w);
    wv.z = packbf((xb.x-mu)*rs*g1.x+b1.x, (xb.y-mu)*rs*g1.y+b1.y);
    wv.w = packbf((xb.z-mu)*rs*g1.z+b1.z, (xb.w-mu)*rs*g1.w+b1.w);
    *(uint4*)&tile[swz64(row, sub*8 + m4*4)] = wv;
  }
}

// D^T = W^T x data; 8 mt tiles, K=128 (for 256-thread kernels).
__device__ __forceinline__ void gemmT8(const u16* __restrict__ PW, int NT, int mtoff,
                                       const u32* __restrict__ tile, int row, int l,
                                       f32x4 acc[8])
{
  int g = l>>4;
  #pragma unroll
  for(int kc=0;kc<4;++kc){
    FragU bf; bf.u = *(const uint4*)&tile[swz64(row, kc*16 + g*4)];
    #pragma unroll
    for(int mt=0;mt<8;++mt){
      FragU af; af.u = ((const uint4*)PW)[(size_t)(kc*NT + mtoff + mt)*64 + l];
      acc[mt] = __builtin_amdgcn_mfma_f32_16x16x32_bf16(af.s, bf.s, acc[mt], 0,0,0);
    }
  }
}

// 4-mt variant for the 8-wave k_edge (each wave owns 4 column tiles).
__device__ __forceinline__ void gemmT4(const u16* __restrict__ PW, int NT, int mtoff,
                                       const u32* __restrict__ tile, int row, int l,
                                       f32x4 acc[4])
{
  int g = l>>4;
  #pragma unroll
  for(int kc=0;kc<4;++kc){
    FragU bf; bf.u = *(const uint4*)&tile[swz64(row, kc*16 + g*4)];
    #pragma unroll
    for(int m=0;m<4;++m){
      FragU af; af.u = ((const uint4*)PW)[(size_t)(kc*NT + mtoff + m)*64 + l];
      acc[m] = __builtin_amdgcn_mfma_f32_16x16x32_bf16(af.s, bf.s, acc[m], 0,0,0);
    }
  }
}

// K=256 variant (8 kc) reading from [64][256] tile
__device__ __forceinline__ void gemmT8_k256(const u16* __restrict__ PW,
                                            const u32* __restrict__ tile, int row, int l,
                                            f32x4 acc[8])
{
  int g = l>>4;
  #pragma unroll
  for(int kc=0;kc<8;++kc){
    FragU bf; bf.u = *(const uint4*)&tile[swz128(row, kc*16 + g*4)];
    #pragma unroll
    for(int mt=0;mt<8;++mt){
      FragU af; af.u = ((const uint4*)PW)[(size_t)(kc*8 + mt)*64 + l];
      acc[mt] = __builtin_amdgcn_mfma_f32_16x16x32_bf16(af.s, bf.s, acc[mt], 0,0,0);
    }
  }
}

// Pack all 9 f32 weights into MFMA A-fragment order (bf16), one launch.
__global__ __launch_bounds__(256)
void k_packall(const float* __restrict__ Wq, const float* __restrict__ Wk,
               const float* __restrict__ Wv, const float* __restrict__ We,
               const float* __restrict__ Wg, const float* __restrict__ Woe,
               const float* __restrict__ Wo, const float* __restrict__ W1,
               const float* __restrict__ W2, u16* __restrict__ dst)
{
  int i = blockIdx.x*256 + threadIdx.x;
  const float* src; int N, idx;
  if (i < 7*16384){
    int m = i >> 14; idx = i & 16383; N=128;
    src = (m==0)?Wq:(m==1)?Wk:(m==2)?Wv:(m==3)?We:(m==4)?Wg:(m==5)?Woe:Wo;
  } else if (i < 7*16384 + 32768){ idx = i - 7*16384; N=256; src = W1; }
  else if (i < 7*16384 + 65536){ idx = i - 7*16384 - 32768; N=128; src = W2; }
  else return;
  int j = idx & 7, l = (idx>>3) & 63;
  int rest = idx >> 9;
  int NT = N >> 4;
  int nt = rest % NT, kc = rest / NT;
  int k = kc*32 + (l>>4)*8 + j;
  int n = nt*16 + (l&15);
  union{float f;u32 u;} x; x.f = src[(size_t)k*N + n];
  dst[i] = (u16)((x.u + (((x.u>>16)&1u) + 0x7fffu)) >> 16);
}

// ---------------- CSR build ----------------
__global__ __launch_bounds__(256)
void k_deg(const int* __restrict__ eidx, int* __restrict__ deg){
  int e = blockIdx.x*256 + threadIdx.x;
  if (e < NE) atomicAdd(&deg[eidx[NE+e]], 1);
}

__global__ __launch_bounds__(1024)
void k_scan(const int* __restrict__ deg, int* __restrict__ starts, int* __restrict__ cursor){
  __shared__ int part[1024];
  int t = threadIdx.x;
  const int CH = (NN + 1023)/1024;
  int base = t*CH;
  int s = 0;
  for (int i=0;i<CH;++i){ int idx = base+i; if (idx < NN) s += deg[idx]; }
  part[t] = s; __syncthreads();
  for (int off=1; off<1024; off<<=1){
    int v = (t>=off) ? part[t-off] : 0;
    __syncthreads();
    part[t] += v;
    __syncthreads();
  }
  int pre = (t==0) ? 0 : part[t-1];
  for (int i=0;i<CH;++i){
    int idx = base+i;
    if (idx < NN){ starts[idx]=pre; cursor[idx]=pre; pre += deg[idx]; }
  }
}

__global__ __launch_bounds__(256)
void k_scatter(const int* __restrict__ eidx, int* __restrict__ cursor, int* __restrict__ elist){
  int e = blockIdx.x*256 + threadIdx.x;
  if (e < NE){
    int d = eidx[NE+e];
    int pos = atomicAdd(&cursor[d], 1);
    elist[pos] = e;
  }
}

// ---------------- K1: node LN + q,k,v projections (packed-pair rows) ----------------
__global__ __launch_bounds__(256)
void k_qkv(const float* __restrict__ xin,
           const float* __restrict__ l1g, const float* __restrict__ l1b,
           const u16* __restrict__ pWq, const float* __restrict__ bq,
           const u16* __restrict__ pWk, const float* __restrict__ bk,
           const u16* __restrict__ pWv, const float* __restrict__ bv,
           u32* __restrict__ qv, u32* __restrict__ kv, u32* __restrict__ vv)
{
  __shared__ u32 tile[64*64];
  int t = threadIdx.x;
  long base = (long)blockIdx.x * 64;
  stage_ln(xin, base, NN, l1g, l1b, tile, t);
  __syncthreads();
  int w = t>>6, l = t&63, g = l>>4;
  int row = w*16 + (l&15);
  long node = base + row;
  bool valid = node < NN;

  f32x4 acc[8];
  const u16* pws[3] = {pWq, pWk, pWv};
  const float* bbs[3] = {bq, bk, bv};
  u32* outs[3] = {qv, kv, vv};
  #pragma unroll
  for(int s3=0;s3<3;++s3){
    #pragma unroll
    for(int mt=0;mt<8;++mt) acc[mt] = (f32x4){0.f,0.f,0.f,0.f};
    gemmT8(pws[s3], 8, 0, tile, row, l, acc);
    if (valid){
      u32* op = outs[s3] + node*64;
      #pragma unroll
      for(int mt=0;mt<8;++mt){
        float4 bb = *(const float4*)(bbs[s3] + mt*16 + g*4);
        uint2 o;
        o.x = packbf(acc[mt][0]+bb.x, acc[mt][1]+bb.y);
        o.y = packbf(acc[mt][2]+bb.z, acc[mt][3]+bb.w);
        *(uint2*)(op + mt*8 + g*2) = o;
      }
    }
  }
}

// ---------------- K2: fused edge pass, 8 waves (mt-split), inline gathers ----------
__global__ __launch_bounds__(512)
void k_edge(const float* __restrict__ ein,
            const float* __restrict__ l1eg, const float* __restrict__ l1eb,
            const u16* __restrict__ pWg, const float* __restrict__ bg,
            const u16* __restrict__ pWe, const float* __restrict__ be,
            const u16* __restrict__ pWoe, const float* __restrict__ boe,
            const int* __restrict__ eidx,
            const u32* __restrict__ qv, const u32* __restrict__ kv, const u32* __restrict__ vv,
            u32* __restrict__ gvp, float* __restrict__ escp,
            float* __restrict__ eout)
{
  __shared__ u32 tile[64*64];
  int t = threadIdx.x;
  long base = (long)blockIdx.x * 64;
  stage_ln8(ein, base, l1eg, l1eb, tile, t);

  int w = t>>6, l = t&63, g = l>>4;
  int rg = w&3, half = w>>2;            // wave = (row-group, mt-half)
  int row = rg*16 + (l&15);
  long edge = base + row;
  int s_ = eidx[edge], d_ = eidx[NE + edge];
  __syncthreads();

  // q/k gathers for my 4 mt tiles -- fly under the We GEMM
  uint2 qw[4], kw[4];
  #pragma unroll
  for(int m=0;m<4;++m){
    int mt = half*4 + m;
    qw[m] = *(const uint2*)(qv + (size_t)d_*64 + mt*8 + g*2);
    kw[m] = *(const uint2*)(kv + (size_t)s_*64 + mt*8 + g*2);
  }

  // s_elt = LN(e)@We + be + q[dst]*k[src]; scores -> esc
  f32x4 acc[4];
  #pragma unroll
  for(int m=0;m<4;++m) acc[m] = (f32x4){0.f,0.f,0.f,0.f};
  gemmT4(pWe, 8, half*4, tile, row, l, acc);
  float esc4[4];
  #pragma unroll
  for(int m=0;m<4;++m){
    int mt = half*4 + m;
    float4 bb = *(const float4*)(be + mt*16 + g*4);
    acc[m][0] += bb.x + bflo(qw[m].x)*bflo(kw[m].x);
    acc[m][1] += bb.y + bfhi(qw[m].x)*bfhi(kw[m].x);
    acc[m][2] += bb.z + bflo(qw[m].y)*bflo(kw[m].y);
    acc[m][3] += bb.w + bfhi(qw[m].y)*bfhi(kw[m].y);
    float ps = acc[m][0]+acc[m][1]+acc[m][2]+acc[m][3];
    ps += __shfl_xor(ps, 16);
    ps += __shfl_xor(ps, 32);                 // sum over all 16 feats of head mt
    float sc = fminf(fmaxf(ps*0.25f, -5.f), 5.f);
    esc4[m] = __expf(sc);                     // clipped => no max-subtract needed
  }
  // store esc (float4 per lane, half-offset)
  if (g==0){
    float4 e0 = {esc4[0],esc4[1],esc4[2],esc4[3]};
    *(float4*)(escp + (size_t)edge*8 + half*4) = e0;
  }
  // v gather -- flies under the Wg GEMM
  uint2 vw[4];
  #pragma unroll
  for(int m=0;m<4;++m) vw[m] = *(const uint2*)(vv + (size_t)s_*64 + (half*4+m)*8 + g*2);

  // gate = sigmoid(LN(e)@Wg + bg); gv = gate (x) v[src]  (edge-order linear writes)
  f32x4 gac[4];
  #pragma unroll
  for(int m=0;m<4;++m) gac[m] = (f32x4){0.f,0.f,0.f,0.f};
  gemmT4(pWg, 8, half*4, tile, row, l, gac);
  #pragma unroll
  for(int m=0;m<4;++m){
    int mt = half*4 + m;
    float4 bb = *(const float4*)(bg + mt*16 + g*4);
    float g0 = 1.f/(1.f+__expf(-(gac[m][0]+bb.x)));
    float g1 = 1.f/(1.f+__expf(-(gac[m][1]+bb.y)));
    float g2 = 1.f/(1.f+__expf(-(gac[m][2]+bb.z)));
    float g3 = 1.f/(1.f+__expf(-(gac[m][3]+bb.w)));
    uint2 o;
    o.x = packbf(g0*bflo(vw[m].x), g1*bfhi(vw[m].x));
    o.y = packbf(g2*bflo(vw[m].y), g3*bfhi(vw[m].y));
    *(uint2*)(gvp + (size_t)edge*64 + mt*8 + g*2) = o;
  }
  __syncthreads();               // all waves done reading LN tile
  // write s_elt (bf16) into tile (B-layout for Woe GEMM)
  #pragma unroll
  for(int m=0;m<4;++m){
    int mt = half*4 + m;
    uint2 o;
    o.x = packbf(acc[m][0], acc[m][1]);
    o.y = packbf(acc[m][2], acc[m][3]);
    *(uint2*)&tile[swz64(row, mt*8 + g*2)] = o;
  }
  __syncthreads();
  // e_out = e_in + s_elt@Woe + boe
  f32x4 oac[4];
  #pragma unroll
  for(int m=0;m<4;++m) oac[m] = (f32x4){0.f,0.f,0.f,0.f};
  gemmT4(pWoe, 8, half*4, tile, row, l, oac);
  #pragma unroll
  for(int m=0;m<4;++m){
    int mt = half*4 + m;
    float4 bb = *(const float4*)(boe + mt*16 + g*4);
    float4 er = *(const float4*)(ein + edge*128 + mt*16 + g*4);
    float4 o;
    o.x = er.x + oac[m][0] + bb.x;
    o.y = er.y + oac[m][1] + bb.y;
    o.z = er.z + oac[m][2] + bb.z;
    o.w = er.w + oac[m][3] + bb.w;
    *(float4*)(eout + edge*128 + mt*16 + g*4) = o;
  }
}

// ---------------- K2b: per-node aggregation over CSR (elist), packed output --------
__global__ __launch_bounds__(256)
void k_agg(const u32* __restrict__ gvp, const float* __restrict__ escp,
           const int* __restrict__ elist, const int* __restrict__ starts,
           const int* __restrict__ ends, u32* __restrict__ xattnb)
{
  int w = threadIdx.x>>6, l = threadIdx.x&63;
  long n = (long)blockIdx.x*4 + w;
  if (n >= NN) return;
  int h = l>>3;                       // head for feats 2l,2l+1
  int s = starts[n], e = ends[n];
  float s0=0.f, s1=0.f, den=0.f;
  for (int i=s;i<e;++i){
    int ed = elist[i];
    u32 gvw = gvp[(size_t)ed*64 + l];
    float a = escp[(size_t)ed*8 + h];
    s0 += a*bflo(gvw);
    s1 += a*bfhi(gvw);
    den += a;
  }
  float inv = den>0.f ? 1.f/den : 0.f;  // zero in-degree -> 0 (segment_sum semantics)
  xattnb[n*64 + l] = packbf(s0*inv, s1*inv);
}

// ---------------- K3: node epilogue: Wo, LN2, FFN ----------------
__global__ __launch_bounds__(256)
void k_out(const float* __restrict__ xin,
           const u32* __restrict__ xattnb,
           const u16* __restrict__ pWo, const float* __restrict__ bo,
           const float* __restrict__ l2g, const float* __restrict__ l2b,
           const u16* __restrict__ pW1, const float* __restrict__ b1p,
           const u16* __restrict__ pW2, const float* __restrict__ b2p,
           float* __restrict__ xout)
{
  __shared__ u32 tile[64*64];
  __shared__ u32 htile[64*128];
  int t = threadIdx.x;
  long base = (long)blockIdx.x * 64;
  // stage attention output (packed bf16 rows) -> swizzled tile
  {
    int row = t>>2, sub = t&3;
    long node = base + row;
    bool valid = node < NN;
    Chunk c;
    if (valid){
      const uint4* p = (const uint4*)(xattnb + node*64 + sub*16);
      #pragma unroll
      for(int i=0;i<4;++i) c.v[i] = p[i];
    } else {
      #pragma unroll
      for(int i=0;i<16;++i) c.d[i] = 0;
    }
    #pragma unroll
    for(int i=0;i<4;++i)
      *(uint4*)&tile[swz64(row, sub*16 + i*4)] = c.v[i];
  }
  __syncthreads();
  int w = t>>6, l = t&63, g = l>>4;
  int row = w*16 + (l&15);
  long node = base + row;
  bool valid = node < NN;

  // Wo GEMM; xmid = x_in + out@Wo + bo
  f32x4 acc[8], xm[8];
  #pragma unroll
  for(int mt=0;mt<8;++mt) acc[mt] = (f32x4){0.f,0.f,0.f,0.f};
  gemmT8(pWo, 8, 0, tile, row, l, acc);
  #pragma unroll
  for(int mt=0;mt<8;++mt){
    float4 bb = *(const float4*)(bo + mt*16 + g*4);
    float4 xr = valid ? *(const float4*)(xin + node*128 + mt*16 + g*4) : make_float4(0.f,0.f,0.f,0.f);
    xm[mt][0] = xr.x + acc[mt][0] + bb.x;
    xm[mt][1] = xr.y + acc[mt][1] + bb.y;
    xm[mt][2] = xr.z + acc[mt][2] + bb.z;
    xm[mt][3] = xr.w + acc[mt][3] + bb.w;
  }
  // LN2 in-register
  float s=0.f, s2=0.f;
  #pragma unroll
  for(int mt=0;mt<8;++mt){
    s  += xm[mt][0]+xm[mt][1]+xm[mt][2]+xm[mt][3];
    s2 += xm[mt][0]*xm[mt][0]+xm[mt][1]*xm[mt][1]+xm[mt][2]*xm[mt][2]+xm[mt][3]*xm[mt][3];
  }
  s  += __shfl_xor(s,16);  s  += __shfl_xor(s,32);
  s2 += __shfl_xor(s2,16); s2 += __shfl_xor(s2,32);
  float mu  = s*(1.f/128.f);
  float var = fmaxf(s2*(1.f/128.f) - mu*mu, 0.f);
  float rs  = rsqrtf(var + 1e-5f);
  __syncthreads();              // done reading tile (Wo B-frags)
  #pragma unroll
  for(int mt=0;mt<8;++mt){
    float4 gg = *(const float4*)(l2g + mt*16 + g*4);
    float4 bb = *(const float4*)(l2b + mt*16 + g*4);
    float h0 = (xm[mt][0]-mu)*rs*gg.x + bb.x;
    float h1 = (xm[mt][1]-mu)*rs*gg.y + bb.y;
    float h2 = (xm[mt][2]-mu)*rs*gg.z + bb.z;
    float h3 = (xm[mt][3]-mu)*rs*gg.w + bb.w;
    uint2 o; o.x = packbf(h0,h1); o.y = packbf(h2,h3);
    *(uint2*)&tile[swz64(row, mt*8 + g*2)] = o;
  }
  __syncthreads();
  // FFN layer 1 (256 outs in two halves), relu -> htile
  #pragma unroll
  for(int half=0; half<2; ++half){
    f32x4 dh[8];
    #pragma unroll
    for(int mt=0;mt<8;++mt) dh[mt] = (f32x4){0.f,0.f,0.f,0.f};
    gemmT8(pW1, 16, half*8, tile, row, l, dh);
    #pragma unroll
    for(int mt=0;mt<8;++mt){
      int feat = half*128 + mt*16 + g*4;
      float4 bb = *(const float4*)(b1p + feat);
      float h0 = fmaxf(dh[mt][0]+bb.x, 0.f);
      float h1 = fmaxf(dh[mt][1]+bb.y, 0.f);
      float h2 = fmaxf(dh[mt][2]+bb.z, 0.f);
      float h3 = fmaxf(dh[mt][3]+bb.w, 0.f);
      uint2 o; o.x = packbf(h0,h1); o.y = packbf(h2,h3);
      *(uint2*)&htile[swz128(row, feat>>1)] = o;
    }
  }
  __syncthreads();
  // FFN layer 2 (K=256) + residual
  f32x4 oacc[8];
  #pragma unroll
  for(int mt=0;mt<8;++mt) oacc[mt] = (f32x4){0.f,0.f,0.f,0.f};
  gemmT8_k256(pW2, htile, row, l, oacc);
  if (valid){
    #pragma unroll
    for(int mt=0;mt<8;++mt){
      float4 bb = *(const float4*)(b2p + mt*16 + g*4);
      float4 o;
      o.x = xm[mt][0] + oacc[mt][0] + bb.x;
      o.y = xm[mt][1] + oacc[mt][1] + bb.y;
      o.z = xm[mt][2] + oacc[mt][2] + bb.z;
      o.w = xm[mt][3] + oacc[mt][3] + bb.w;
      *(float4*)(xout + node*128 + mt*16 + g*4) = o;
    }
  }
}

extern "C" void kernel_launch(void* const* d_in, const int* in_sizes, int n_in,
                              void* d_out, int out_size, void* d_ws, size_t ws_size,
                              hipStream_t stream) {
  (void)in_sizes; (void)n_in; (void)out_size; (void)ws_size;
  const float* xin = (const float*)d_in[0];
  const float* ein = (const float*)d_in[1];
  const float* Wq = (const float*)d_in[2];  const float* bq = (const float*)d_in[3];
  const float* Wk = (const float*)d_in[4];  const float* bk = (const float*)d_in[5];
  const float* Wv = (const float*)d_in[6];  const float* bv = (const float*)d_in[7];
  const float* We = (const float*)d_in[8];  const float* be = (const float*)d_in[9];
  const float* Wg = (const float*)d_in[10]; const float* bg = (const float*)d_in[11];
  const float* Wo = (const float*)d_in[12]; const float* bo = (const float*)d_in[13];
  const float* Woe= (const float*)d_in[14]; const float* boe= (const float*)d_in[15];
  const float* l1g= (const float*)d_in[16]; const float* l1b= (const float*)d_in[17];
  const float* l1eg=(const float*)d_in[18]; const float* l1eb=(const float*)d_in[19];
  const float* l2g= (const float*)d_in[20]; const float* l2b= (const float*)d_in[21];
  const float* W1 = (const float*)d_in[22]; const float* b1 = (const float*)d_in[23];
  const float* W2 = (const float*)d_in[24]; const float* b2 = (const float*)d_in[25];
  const int* eidx = (const int*)d_in[26];

  float* xout = (float*)d_out;
  float* eout = xout + (size_t)NN*128;

  // ws: esc [NE*8 f32] | gv [NE*64 u32] | qv,kv,vv [NN*64 u32] | xattnb [NN*64 u32]
  //     | deg,starts,cursor [NN] | elist [NE] | packed W (bf16)
  float* escp = (float*)d_ws;
  u32* gvp = (u32*)(escp + (size_t)NE*8);
  u32* qv = gvp + (size_t)NE*64;
  u32* kv = qv + (size_t)NN*64;
  u32* vv = kv + (size_t)NN*64;
  u32* xattnb = vv + (size_t)NN*64;
  int* deg = (int*)(xattnb + (size_t)NN*64);
  int* starts = deg + NN;
  int* cursor = starts + NN;
  int* elist = cursor + NN;
  u16* pw  = (u16*)(elist + NE);
  u16* pWq = pw;            u16* pWk = pWq + 16384;  u16* pWv = pWk + 16384;
  u16* pWe = pWv + 16384;   u16* pWg = pWe + 16384;  u16* pWoe= pWg + 16384;
  u16* pWo = pWoe + 16384;  u16* pW1 = pWo + 16384;  u16* pW2 = pW1 + 32768;

  k_packall<<<(7*16384+65536+255)/256, 256, 0, stream>>>(Wq,Wk,Wv,We,Wg,Woe,Wo,W1,W2, pw);

  // CSR build
  hipMemsetAsync(deg, 0, NN*sizeof(int), stream);
  k_deg<<<(NE+255)/256, 256, 0, stream>>>(eidx, deg);
  k_scan<<<1, 1024, 0, stream>>>(deg, starts, cursor);
  k_scatter<<<(NE+255)/256, 256, 0, stream>>>(eidx, cursor, elist);

  k_qkv<<<(NN+63)/64, 256, 0, stream>>>(xin, l1g, l1b, pWq, bq, pWk, bk, pWv, bv, qv, kv, vv);
  k_edge<<<NE/64, 512, 0, stream>>>(ein, l1eg, l1eb, pWg, bg, pWe, be, pWoe, boe,
                                    eidx, qv, kv, vv, gvp, escp, eout);
  k_agg<<<(NN+3)/4, 256, 0, stream>>>(gvp, escp, elist, starts, cursor, xattnb);
  k_out<<<(NN+63)/64, 256, 0, stream>>>(xin, xattnb, pWo, bo, l2g, l2b,
                                        pW1, b1, pW2, b2, xout);
}